// Round 1
// baseline (656.409 us; speedup 1.0000x reference)
//
#include <hip/hip_runtime.h>
#include <math.h>

// Problem constants: B=4, N=1024 (H=W=32), C=512, heads=8, hd=64, wsz=8
#define NTOK 1024
#define CDIM 512

// ---------------------------------------------------------------------------
// GEMM: Y[M,512] = X[M,512] @ W[512,512]^T + b    (M = 4096, grid (8,64))
// 64x64 tile, 256 threads, 4x4 microtile, fp32.
// ---------------------------------------------------------------------------
__global__ __launch_bounds__(256) void gemm_xwT(
    const float* __restrict__ X, const float* __restrict__ W,
    const float* __restrict__ B, float* __restrict__ Y) {
  __shared__ float Xs[64][68];
  __shared__ float Ws[64][68];
  int tid = threadIdx.x;
  int row0 = blockIdx.y * 64;
  int col0 = blockIdx.x * 64;
  int tr = (tid >> 4) << 2;  // 0..60
  int tc = (tid & 15) << 2;  // 0..60
  float acc[4][4] = {};
  for (int s = 0; s < 512; s += 64) {
    __syncthreads();
    // stage 64x64 tiles of X and W (rows of 64 floats, float4 loads)
    for (int e = tid; e < 1024; e += 256) {
      int r = e >> 4;
      int k4 = (e & 15) << 2;
      float4 xv = *(const float4*)&X[(size_t)(row0 + r) * 512 + s + k4];
      float4 wv = *(const float4*)&W[(size_t)(col0 + r) * 512 + s + k4];
      *(float4*)&Xs[r][k4] = xv;
      *(float4*)&Ws[r][k4] = wv;
    }
    __syncthreads();
    #pragma unroll
    for (int k4 = 0; k4 < 64; k4 += 4) {
      float4 xa[4], wa[4];
      #pragma unroll
      for (int i = 0; i < 4; ++i) xa[i] = *(const float4*)&Xs[tr + i][k4];
      #pragma unroll
      for (int j = 0; j < 4; ++j) wa[j] = *(const float4*)&Ws[tc + j][k4];
      #pragma unroll
      for (int i = 0; i < 4; ++i)
        #pragma unroll
        for (int j = 0; j < 4; ++j)
          acc[i][j] += xa[i].x * wa[j].x + xa[i].y * wa[j].y +
                       xa[i].z * wa[j].z + xa[i].w * wa[j].w;
    }
  }
  #pragma unroll
  for (int i = 0; i < 4; ++i) {
    float4 o;
    o.x = acc[i][0] + B[col0 + tc + 0];
    o.y = acc[i][1] + B[col0 + tc + 1];
    o.z = acc[i][2] + B[col0 + tc + 2];
    o.w = acc[i][3] + B[col0 + tc + 3];
    *(float4*)&Y[(size_t)(row0 + tr + i) * 512 + col0 + tc] = o;
  }
}

// ---------------------------------------------------------------------------
// Offset network: depthwise 5x5 conv (+bias, zero pad) -> exact GELU ->
// 1x1 (16 out) -> tanh*2 -> sample coords (pixel space). One block per pixel.
// ---------------------------------------------------------------------------
__global__ __launch_bounds__(512) void offset_net(
    const float* __restrict__ x, const float* __restrict__ dw_w,
    const float* __restrict__ dw_b, const float* __restrict__ off_w,
    float* __restrict__ samp) {
  __shared__ float hbuf[512];
  __shared__ float obuf[16];
  int pix = blockIdx.x;  // 0..4095
  int b = pix >> 10;
  int n = pix & 1023;
  int y = n >> 5, xx = n & 31;
  int c = threadIdx.x;
  float s = dw_b[c];
  #pragma unroll
  for (int ky = 0; ky < 5; ++ky) {
    int yy = y + ky - 2;
    if (yy < 0 || yy >= 32) continue;
    #pragma unroll
    for (int kx = 0; kx < 5; ++kx) {
      int xc = xx + kx - 2;
      if (xc < 0 || xc >= 32) continue;
      s += x[((size_t)b * 1024 + yy * 32 + xc) * 512 + c] * dw_w[c * 25 + ky * 5 + kx];
    }
  }
  float g = 0.5f * s * (1.0f + erff(s * 0.70710678118654752f));
  hbuf[c] = g;
  __syncthreads();
  int o = threadIdx.x >> 5;   // 0..15
  int lg = threadIdx.x & 31;  // 32 lanes per output (within one wave half)
  float p = 0.f;
  for (int k = lg; k < 512; k += 32) p += hbuf[k] * off_w[o * 512 + k];
  #pragma unroll
  for (int m = 1; m < 32; m <<= 1) p += __shfl_xor(p, m);
  if (lg == 0) obuf[o] = tanhf(p) * 2.0f;
  __syncthreads();
  if (threadIdx.x < 8) {
    int h = threadIdx.x;
    float gx = -1.0f + 2.0f * (float)xx / 31.0f;
    float gy = -1.0f + 2.0f * (float)y / 31.0f;
    float sx = gx + obuf[2 * h];
    float sy = gy + obuf[2 * h + 1];
    sx = fminf(fmaxf(sx, -1.0f), 1.0f);
    sy = fminf(fmaxf(sy, -1.0f), 1.0f);
    float2 pc;
    pc.x = (sx + 1.0f) * 16.0f - 0.5f;  // pixel coords, align_corners=False
    pc.y = (sy + 1.0f) * 16.0f - 0.5f;
    ((float2*)samp)[(size_t)(b * 8 + h) * 1024 + n] = pc;
  }
}

// ---------------------------------------------------------------------------
// Bilinear grid-sample (zeros padding) of K and V: Ks/Vs [B*heads][N][64]
// grid (256, 32), 256 threads: 4 sample points per block, 64 channels each.
// ---------------------------------------------------------------------------
__global__ __launch_bounds__(256) void grid_sample(
    const float* __restrict__ K, const float* __restrict__ V,
    const float* __restrict__ samp, float* __restrict__ Ks,
    float* __restrict__ Vs) {
  int bh = blockIdx.y;
  int b = bh >> 3, h = bh & 7;
  int j = blockIdx.x * 4 + (threadIdx.x >> 6);
  int d = threadIdx.x & 63;
  float2 pc = ((const float2*)samp)[(size_t)bh * 1024 + j];
  float gx = pc.x, gy = pc.y;
  float x0 = floorf(gx), y0 = floorf(gy);
  float aK = 0.f, aV = 0.f;
  #pragma unroll
  for (int dy = 0; dy < 2; ++dy)
    #pragma unroll
    for (int dx = 0; dx < 2; ++dx) {
      float xi = x0 + (float)dx, yi = y0 + (float)dy;
      float w = (1.0f - fabsf(gx - xi)) * (1.0f - fabsf(gy - yi));
      if (xi >= 0.f && xi < 32.f && yi >= 0.f && yi < 32.f) {
        size_t base = ((size_t)b * 1024 + (int)yi * 32 + (int)xi) * 512 + h * 64 + d;
        aK += K[base] * w;
        aV += V[base] * w;
      }
    }
  size_t oidx = ((size_t)bh * 1024 + j) * 64 + d;
  Ks[oidx] = aK;
  Vs[oidx] = aV;
}

// ---------------------------------------------------------------------------
// Relative-position bias: bicubic-upsample (4-tap per axis) of the 64x64
// table-gathered bias to 1024x1024. One block per output row.
// ---------------------------------------------------------------------------
__device__ __forceinline__ void bicubic_taps(int i, float* w, int* idx) {
  const float a = -0.75f;
  float src = ((float)i + 0.5f) * 0.0625f - 0.5f;  // exact in fp32
  float fi = floorf(src);
  int i0 = (int)fi;
  float t = src - fi;
  #pragma unroll
  for (int k = -1; k <= 2; ++k) {
    float d = fabsf(t - (float)k);
    float wv;
    if (d <= 1.0f)
      wv = ((a + 2.0f) * d - (a + 3.0f)) * d * d + 1.0f;
    else if (d < 2.0f)
      wv = a * (((d - 5.0f) * d + 8.0f) * d - 4.0f);
    else
      wv = 0.0f;
    int ic = i0 + k;
    ic = ic < 0 ? 0 : (ic > 63 ? 63 : ic);
    w[k + 1] = wv;
    idx[k + 1] = ic;
  }
}

__global__ __launch_bounds__(256) void bias_kernel(
    const float* __restrict__ table, float* __restrict__ bias) {
  __shared__ float tab[225];
  int i = blockIdx.x;
  int tid = threadIdx.x;
  if (tid < 225) tab[tid] = table[tid];
  __syncthreads();
  float wA[4]; int iA[4];
  bicubic_taps(i, wA, iA);
  for (int j = tid; j < 1024; j += 256) {
    float wB[4]; int iB[4];
    bicubic_taps(j, wB, iB);
    float sum = 0.f;
    #pragma unroll
    for (int ka = 0; ka < 4; ++ka) {
      int pa = iA[ka];
      int py = pa >> 3, px = pa & 7;
      float wa = wA[ka];
      #pragma unroll
      for (int kb = 0; kb < 4; ++kb) {
        int qb = iB[kb];
        int qy = qb >> 3, qx = qb & 7;
        sum += wa * wB[kb] * tab[(py - qy + 7) * 15 + (px - qx + 7)];
      }
    }
    bias[(size_t)i * 1024 + j] = sum;
  }
}

// ---------------------------------------------------------------------------
// Attention: per (bh, 64-row i-tile): scores = (Q/8)·Ks^T + bias, online
// softmax, out = P·Vs. 256 threads, 4x4 microtiles. Ps reuses the Ks LDS.
// ---------------------------------------------------------------------------
__global__ __launch_bounds__(256) void attn_kernel(
    const float* __restrict__ Q, const float* __restrict__ Ks,
    const float* __restrict__ Vs, const float* __restrict__ bias,
    float* __restrict__ out) {
  __shared__ float Qs[64][68];
  __shared__ float KsS[64][68];  // also reused as P tile
  __shared__ float VsS[64][68];
  int tid = threadIdx.x;
  int bh = blockIdx.y;
  int b = bh >> 3, h = bh & 7;
  int i0 = blockIdx.x * 64;
  for (int e = tid; e < 1024; e += 256) {
    int r = e >> 4, k4 = (e & 15) << 2;
    float4 v = *(const float4*)&Q[((size_t)b * 1024 + i0 + r) * 512 + h * 64 + k4];
    v.x *= 0.125f; v.y *= 0.125f; v.z *= 0.125f; v.w *= 0.125f;
    *(float4*)&Qs[r][k4] = v;
  }
  int tr = (tid >> 4) << 2;
  int tc = (tid & 15) << 2;
  float m[4], l[4], acc[4][4] = {};
  #pragma unroll
  for (int i = 0; i < 4; ++i) { m[i] = -INFINITY; l[i] = 0.f; }

  for (int jt = 0; jt < 16; ++jt) {
    __syncthreads();  // previous-iter LDS reads done
    for (int e = tid; e < 1024; e += 256) {
      int r = e >> 4, k4 = (e & 15) << 2;
      size_t base = ((size_t)bh * 1024 + jt * 64 + r) * 64 + k4;
      *(float4*)&KsS[r][k4] = *(const float4*)&Ks[base];
      *(float4*)&VsS[r][k4] = *(const float4*)&Vs[base];
    }
    __syncthreads();
    // scores 4x4 (bias preloaded)
    float s[4][4];
    #pragma unroll
    for (int i = 0; i < 4; ++i) {
      float4 bv = *(const float4*)&bias[(size_t)(i0 + tr + i) * 1024 + jt * 64 + tc];
      s[i][0] = bv.x; s[i][1] = bv.y; s[i][2] = bv.z; s[i][3] = bv.w;
    }
    #pragma unroll
    for (int k4 = 0; k4 < 64; k4 += 4) {
      float4 qa[4], ka[4];
      #pragma unroll
      for (int i = 0; i < 4; ++i) qa[i] = *(const float4*)&Qs[tr + i][k4];
      #pragma unroll
      for (int j = 0; j < 4; ++j) ka[j] = *(const float4*)&KsS[tc + j][k4];
      #pragma unroll
      for (int i = 0; i < 4; ++i)
        #pragma unroll
        for (int j = 0; j < 4; ++j)
          s[i][j] += qa[i].x * ka[j].x + qa[i].y * ka[j].y +
                     qa[i].z * ka[j].z + qa[i].w * ka[j].w;
    }
    __syncthreads();  // all KsS reads done; safe to overwrite with P
    // online softmax update (row groups of 16 lanes)
    #pragma unroll
    for (int i = 0; i < 4; ++i) {
      float mt = fmaxf(fmaxf(s[i][0], s[i][1]), fmaxf(s[i][2], s[i][3]));
      #pragma unroll
      for (int msk = 1; msk < 16; msk <<= 1) mt = fmaxf(mt, __shfl_xor(mt, msk));
      float mn = fmaxf(m[i], mt);
      float sc = expf(m[i] - mn);
      float pr0 = expf(s[i][0] - mn), pr1 = expf(s[i][1] - mn);
      float pr2 = expf(s[i][2] - mn), pr3 = expf(s[i][3] - mn);
      float ts = pr0 + pr1 + pr2 + pr3;
      #pragma unroll
      for (int msk = 1; msk < 16; msk <<= 1) ts += __shfl_xor(ts, msk);
      l[i] = l[i] * sc + ts;
      m[i] = mn;
      acc[i][0] *= sc; acc[i][1] *= sc; acc[i][2] *= sc; acc[i][3] *= sc;
      float4 pv = make_float4(pr0, pr1, pr2, pr3);
      *(float4*)&KsS[tr + i][tc] = pv;  // P tile
    }
    __syncthreads();
    // PV accumulate
    #pragma unroll
    for (int j4 = 0; j4 < 64; j4 += 4) {
      float4 pv[4], vv[4];
      #pragma unroll
      for (int i = 0; i < 4; ++i) pv[i] = *(const float4*)&KsS[tr + i][j4];
      #pragma unroll
      for (int u = 0; u < 4; ++u) vv[u] = *(const float4*)&VsS[j4 + u][tc];
      #pragma unroll
      for (int i = 0; i < 4; ++i) {
        acc[i][0] += pv[i].x * vv[0].x + pv[i].y * vv[1].x + pv[i].z * vv[2].x + pv[i].w * vv[3].x;
        acc[i][1] += pv[i].x * vv[0].y + pv[i].y * vv[1].y + pv[i].z * vv[2].y + pv[i].w * vv[3].y;
        acc[i][2] += pv[i].x * vv[0].z + pv[i].y * vv[1].z + pv[i].z * vv[2].z + pv[i].w * vv[3].z;
        acc[i][3] += pv[i].x * vv[0].w + pv[i].y * vv[1].w + pv[i].z * vv[2].w + pv[i].w * vv[3].w;
      }
    }
  }
  #pragma unroll
  for (int i = 0; i < 4; ++i) {
    float inv = 1.0f / l[i];
    float4 o = make_float4(acc[i][0] * inv, acc[i][1] * inv, acc[i][2] * inv, acc[i][3] * inv);
    *(float4*)&out[((size_t)b * 1024 + i0 + tr + i) * 512 + h * 64 + tc] = o;
  }
}

// ---------------------------------------------------------------------------
extern "C" void kernel_launch(void* const* d_in, const int* in_sizes, int n_in,
                              void* d_out, int out_size, void* d_ws, size_t ws_size,
                              hipStream_t stream) {
  const float* x     = (const float*)d_in[0];
  const float* q_w   = (const float*)d_in[1];
  const float* q_b   = (const float*)d_in[2];
  const float* k_w   = (const float*)d_in[3];
  const float* k_b   = (const float*)d_in[4];
  const float* v_w   = (const float*)d_in[5];
  const float* v_b   = (const float*)d_in[6];
  const float* o_w   = (const float*)d_in[7];
  const float* o_b   = (const float*)d_in[8];
  const float* dw_w  = (const float*)d_in[9];
  const float* dw_b  = (const float*)d_in[10];
  const float* off_w = (const float*)d_in[11];
  const float* btab  = (const float*)d_in[12];

  float* ws = (float*)d_ws;
  const size_t SZ = (size_t)4 * 1024 * 512;  // 2M floats
  float* Q    = ws;
  float* K    = ws + SZ;
  float* V    = ws + 2 * SZ;
  float* Ksb  = ws + 3 * SZ;
  float* Vsb  = ws + 4 * SZ;
  float* attn = ws + 5 * SZ;
  float* bias = ws + 6 * SZ;               // 1M floats
  float* samp = ws + 6 * SZ + 1048576;     // 65536 floats (float2 x 32768)

  dim3 gb(8, 64);
  gemm_xwT<<<gb, 256, 0, stream>>>(x, q_w, q_b, Q);
  gemm_xwT<<<gb, 256, 0, stream>>>(x, k_w, k_b, K);
  gemm_xwT<<<gb, 256, 0, stream>>>(x, v_w, v_b, V);
  offset_net<<<4096, 512, 0, stream>>>(x, dw_w, dw_b, off_w, samp);
  grid_sample<<<dim3(256, 32), 256, 0, stream>>>(K, V, samp, Ksb, Vsb);
  bias_kernel<<<1024, 256, 0, stream>>>(btab, bias);
  attn_kernel<<<dim3(16, 32), 256, 0, stream>>>(Q, Ksb, Vsb, bias, attn);
  gemm_xwT<<<gb, 256, 0, stream>>>(attn, o_w, o_b, (float*)d_out);
}

// Round 2
// 605.044 us; speedup vs baseline: 1.0849x; 1.0849x over previous
//
#include <hip/hip_runtime.h>
#include <math.h>

typedef unsigned short ushort;
typedef __attribute__((ext_vector_type(8))) short bf16x8;
typedef __attribute__((ext_vector_type(4))) float f32x4;

#define MFMA16(a, b, c) __builtin_amdgcn_mfma_f32_16x16x32_bf16(a, b, c, 0, 0, 0)
#define GLOAD16(g, l)                                                   \
  __builtin_amdgcn_global_load_lds(                                     \
      (const __attribute__((address_space(1))) unsigned int*)(g),       \
      (__attribute__((address_space(3))) unsigned int*)(l), 16, 0, 0)

__device__ __forceinline__ ushort f2bf(float f) {
  unsigned u = __float_as_uint(f);
  u += 0x7FFFu + ((u >> 16) & 1u);  // RNE
  return (ushort)(u >> 16);
}
__device__ __forceinline__ float bf2f(ushort b) {
  return __uint_as_float(((unsigned)b) << 16);
}

// ---------------------------------------------------------------------------
// Split fp32 -> (hi, lo) bf16 pair.  n4 = element_count/4.
// ---------------------------------------------------------------------------
__global__ __launch_bounds__(256) void split_kernel(
    const float* __restrict__ in, ushort* __restrict__ hi,
    ushort* __restrict__ lo, int n4) {
  int i = blockIdx.x * 256 + threadIdx.x;
  if (i >= n4) return;
  float4 v = ((const float4*)in)[i];
  ushort4 h, l;
  h.x = f2bf(v.x); l.x = f2bf(v.x - bf2f(h.x));
  h.y = f2bf(v.y); l.y = f2bf(v.y - bf2f(h.y));
  h.z = f2bf(v.z); l.z = f2bf(v.z - bf2f(h.z));
  h.w = f2bf(v.w); l.w = f2bf(v.w - bf2f(h.w));
  ((ushort4*)hi)[i] = h;
  ((ushort4*)lo)[i] = l;
}

// ---------------------------------------------------------------------------
// MFMA GEMM: Y[4096,512] = A[4096,512] @ W[512,512]^T + b, hi/lo split bf16.
// Tile 128x64, BK=64, 256 threads (4 waves, 2x2), 16x16x32 MFMA, 3 passes.
// grid (8, 32).
// ---------------------------------------------------------------------------
__global__ __launch_bounds__(256) void gemm_mfma(
    const ushort* __restrict__ Ahi, const ushort* __restrict__ Alo,
    const ushort* __restrict__ Bhi, const ushort* __restrict__ Blo,
    const float* __restrict__ bias, float* __restrict__ Y) {
  __shared__ ushort lds[24576];  // Ahi[128*64] Alo[128*64] Bhi[64*64] Blo[64*64]
  ushort* sAhi = lds;
  ushort* sAlo = lds + 8192;
  ushort* sBhi = lds + 16384;
  ushort* sBlo = lds + 20480;
  int tid = threadIdx.x;
  int lane = tid & 63;
  int w = tid >> 6;
  int m0 = blockIdx.y * 128;
  int n0 = blockIdx.x * 64;
  int wr = (w >> 1) * 64;  // wave row offset in tile
  int wc = (w & 1) * 32;   // wave col offset in tile
  int l8r = lane >> 3;                    // row within an 8-row staging chunk
  int sll = ((lane & 7) ^ l8r) << 3;      // logical slot (ushorts), pre-swizzled
  int l16 = lane & 15, lq = lane >> 4;

  f32x4 acc[4][2];
  f32x4 zero = {0.f, 0.f, 0.f, 0.f};
  #pragma unroll
  for (int m = 0; m < 4; ++m)
    #pragma unroll
    for (int n = 0; n < 2; ++n) acc[m][n] = zero;

  for (int kt = 0; kt < 8; ++kt) {
    int kk = kt * 64;
    __syncthreads();
    #pragma unroll
    for (int q = 0; q < 4; ++q) {
      int ci = w * 4 + q;
      size_t go = (size_t)(m0 + ci * 8 + l8r) * 512 + kk + sll;
      GLOAD16(Ahi + go, sAhi + ci * 512);
      GLOAD16(Alo + go, sAlo + ci * 512);
    }
    #pragma unroll
    for (int q = 0; q < 2; ++q) {
      int ci = w * 2 + q;
      size_t go = (size_t)(n0 + ci * 8 + l8r) * 512 + kk + sll;
      GLOAD16(Bhi + go, sBhi + ci * 512);
      GLOAD16(Blo + go, sBlo + ci * 512);
    }
    __syncthreads();
    #pragma unroll
    for (int ks = 0; ks < 2; ++ks) {
      int slot = ks * 4 + lq;
      bf16x8 ah[4], al[4], bh[2], bl[2];
      #pragma unroll
      for (int m = 0; m < 4; ++m) {
        int r = wr + m * 16 + l16;
        int ph = (slot ^ (r & 7)) << 3;
        ah[m] = *(const bf16x8*)&sAhi[r * 64 + ph];
        al[m] = *(const bf16x8*)&sAlo[r * 64 + ph];
      }
      #pragma unroll
      for (int n = 0; n < 2; ++n) {
        int r = wc + n * 16 + l16;
        int ph = (slot ^ (r & 7)) << 3;
        bh[n] = *(const bf16x8*)&sBhi[r * 64 + ph];
        bl[n] = *(const bf16x8*)&sBlo[r * 64 + ph];
      }
      #pragma unroll
      for (int m = 0; m < 4; ++m)
        #pragma unroll
        for (int n = 0; n < 2; ++n) {
          acc[m][n] = MFMA16(ah[m], bh[n], acc[m][n]);
          acc[m][n] = MFMA16(ah[m], bl[n], acc[m][n]);
          acc[m][n] = MFMA16(al[m], bh[n], acc[m][n]);
        }
    }
  }
  #pragma unroll
  for (int n = 0; n < 2; ++n) {
    int col = n0 + wc + n * 16 + l16;
    float bv = bias[col];
    #pragma unroll
    for (int m = 0; m < 4; ++m) {
      #pragma unroll
      for (int j = 0; j < 4; ++j) {
        int row = m0 + wr + m * 16 + lq * 4 + j;
        Y[(size_t)row * 512 + col] = acc[m][n][j] + bv;
      }
    }
  }
}

// ---------------------------------------------------------------------------
// Offset network: depthwise 5x5 conv -> exact GELU -> 1x1(16) -> tanh*2 ->
// sample coords in pixel space. One block per pixel.
// ---------------------------------------------------------------------------
__global__ __launch_bounds__(512) void offset_net(
    const float* __restrict__ x, const float* __restrict__ dw_w,
    const float* __restrict__ dw_b, const float* __restrict__ off_w,
    float* __restrict__ samp) {
  __shared__ float hbuf[512];
  __shared__ float obuf[16];
  int pix = blockIdx.x;
  int b = pix >> 10;
  int n = pix & 1023;
  int y = n >> 5, xx = n & 31;
  int c = threadIdx.x;
  float s = dw_b[c];
  #pragma unroll
  for (int ky = 0; ky < 5; ++ky) {
    int yy = y + ky - 2;
    if (yy < 0 || yy >= 32) continue;
    #pragma unroll
    for (int kx = 0; kx < 5; ++kx) {
      int xc = xx + kx - 2;
      if (xc < 0 || xc >= 32) continue;
      s += x[((size_t)b * 1024 + yy * 32 + xc) * 512 + c] * dw_w[c * 25 + ky * 5 + kx];
    }
  }
  float g = 0.5f * s * (1.0f + erff(s * 0.70710678118654752f));
  hbuf[c] = g;
  __syncthreads();
  int o = threadIdx.x >> 5;
  int lg = threadIdx.x & 31;
  float p = 0.f;
  for (int k = lg; k < 512; k += 32) p += hbuf[k] * off_w[o * 512 + k];
  #pragma unroll
  for (int m = 1; m < 32; m <<= 1) p += __shfl_xor(p, m);
  if (lg == 0) obuf[o] = tanhf(p) * 2.0f;
  __syncthreads();
  if (threadIdx.x < 8) {
    int h = threadIdx.x;
    float gx = -1.0f + 2.0f * (float)xx / 31.0f;
    float gy = -1.0f + 2.0f * (float)y / 31.0f;
    float sx = fminf(fmaxf(gx + obuf[2 * h], -1.0f), 1.0f);
    float sy = fminf(fmaxf(gy + obuf[2 * h + 1], -1.0f), 1.0f);
    float2 pc;
    pc.x = (sx + 1.0f) * 16.0f - 0.5f;
    pc.y = (sy + 1.0f) * 16.0f - 0.5f;
    ((float2*)samp)[(size_t)(b * 8 + h) * 1024 + n] = pc;
  }
}

// ---------------------------------------------------------------------------
// Bilinear grid-sample (zeros padding) of K and V.
// ---------------------------------------------------------------------------
__global__ __launch_bounds__(256) void grid_sample(
    const float* __restrict__ K, const float* __restrict__ V,
    const float* __restrict__ samp, float* __restrict__ Ks,
    float* __restrict__ Vs) {
  int bh = blockIdx.y;
  int b = bh >> 3, h = bh & 7;
  int j = blockIdx.x * 4 + (threadIdx.x >> 6);
  int d = threadIdx.x & 63;
  float2 pc = ((const float2*)samp)[(size_t)bh * 1024 + j];
  float gx = pc.x, gy = pc.y;
  float x0 = floorf(gx), y0 = floorf(gy);
  float aK = 0.f, aV = 0.f;
  #pragma unroll
  for (int dy = 0; dy < 2; ++dy)
    #pragma unroll
    for (int dx = 0; dx < 2; ++dx) {
      float xi = x0 + (float)dx, yi = y0 + (float)dy;
      float wgt = (1.0f - fabsf(gx - xi)) * (1.0f - fabsf(gy - yi));
      if (xi >= 0.f && xi < 32.f && yi >= 0.f && yi < 32.f) {
        size_t base = ((size_t)b * 1024 + (int)yi * 32 + (int)xi) * 512 + h * 64 + d;
        aK += K[base] * wgt;
        aV += V[base] * wgt;
      }
    }
  size_t oidx = ((size_t)bh * 1024 + j) * 64 + d;
  Ks[oidx] = aK;
  Vs[oidx] = aV;
}

// ---------------------------------------------------------------------------
// Relative-position bias via 4-tap bicubic along both axes.
// ---------------------------------------------------------------------------
__device__ __forceinline__ void bicubic_taps(int i, float* w, int* idx) {
  const float a = -0.75f;
  float src = ((float)i + 0.5f) * 0.0625f - 0.5f;
  float fi = floorf(src);
  int i0 = (int)fi;
  float t = src - fi;
  #pragma unroll
  for (int k = -1; k <= 2; ++k) {
    float d = fabsf(t - (float)k);
    float wv;
    if (d <= 1.0f)
      wv = ((a + 2.0f) * d - (a + 3.0f)) * d * d + 1.0f;
    else if (d < 2.0f)
      wv = a * (((d - 5.0f) * d + 8.0f) * d - 4.0f);
    else
      wv = 0.0f;
    int ic = i0 + k;
    ic = ic < 0 ? 0 : (ic > 63 ? 63 : ic);
    w[k + 1] = wv;
    idx[k + 1] = ic;
  }
}

__global__ __launch_bounds__(256) void bias_kernel(
    const float* __restrict__ table, float* __restrict__ bias) {
  __shared__ float tab[225];
  int i = blockIdx.x;
  int tid = threadIdx.x;
  if (tid < 225) tab[tid] = table[tid];
  __syncthreads();
  float wA[4]; int iA[4];
  bicubic_taps(i, wA, iA);
  for (int j = tid; j < 1024; j += 256) {
    float wB[4]; int iB[4];
    bicubic_taps(j, wB, iB);
    float sum = 0.f;
    #pragma unroll
    for (int ka = 0; ka < 4; ++ka) {
      int pa = iA[ka];
      int py = pa >> 3, px = pa & 7;
      float wa = wA[ka];
      #pragma unroll
      for (int kb = 0; kb < 4; ++kb) {
        int qb = iB[kb];
        int qy = qb >> 3, qx = qb & 7;
        sum += wa * wB[kb] * tab[(py - qy + 7) * 15 + (px - qx + 7)];
      }
    }
    bias[(size_t)i * 1024 + j] = sum;
  }
}

// ---------------------------------------------------------------------------
// fp32 attention with swizzled LDS (column-block rotation kills the 8-way
// bank conflicts on the K^T fragment reads).
// ---------------------------------------------------------------------------
__device__ __forceinline__ int swc(int r, int cb) {
  return ((cb + (r >> 2)) & 15) << 2;
}

__global__ __launch_bounds__(256) void attn_kernel(
    const float* __restrict__ Q, const float* __restrict__ Ks,
    const float* __restrict__ Vs, const float* __restrict__ bias,
    float* __restrict__ out) {
  __shared__ float Qs[64][68];
  __shared__ float KsS[64][68];  // reused as P tile
  __shared__ float VsS[64][68];
  int tid = threadIdx.x;
  int bh = blockIdx.y;
  int b = bh >> 3, h = bh & 7;
  int i0 = blockIdx.x * 64;
  for (int e = tid; e < 1024; e += 256) {
    int r = e >> 4, cb = e & 15;
    float4 v = *(const float4*)&Q[((size_t)b * 1024 + i0 + r) * 512 + h * 64 + (cb << 2)];
    v.x *= 0.125f; v.y *= 0.125f; v.z *= 0.125f; v.w *= 0.125f;
    *(float4*)&Qs[r][swc(r, cb)] = v;
  }
  int tr = (tid >> 4) << 2;
  int tc = (tid & 15) << 2;
  float m[4], l[4], acc[4][4] = {};
  #pragma unroll
  for (int i = 0; i < 4; ++i) { m[i] = -INFINITY; l[i] = 0.f; }

  for (int jt = 0; jt < 16; ++jt) {
    __syncthreads();
    for (int e = tid; e < 1024; e += 256) {
      int r = e >> 4, cb = e & 15;
      size_t base = ((size_t)bh * 1024 + jt * 64 + r) * 64 + (cb << 2);
      int pc = swc(r, cb);
      *(float4*)&KsS[r][pc] = *(const float4*)&Ks[base];
      *(float4*)&VsS[r][pc] = *(const float4*)&Vs[base];
    }
    __syncthreads();
    float s[4][4];
    #pragma unroll
    for (int i = 0; i < 4; ++i) {
      float4 bv = *(const float4*)&bias[(size_t)(i0 + tr + i) * 1024 + jt * 64 + tc];
      s[i][0] = bv.x; s[i][1] = bv.y; s[i][2] = bv.z; s[i][3] = bv.w;
    }
    #pragma unroll
    for (int k4 = 0; k4 < 64; k4 += 4) {
      int cb = k4 >> 2;
      float4 qa[4], ka[4];
      #pragma unroll
      for (int i = 0; i < 4; ++i) qa[i] = *(const float4*)&Qs[tr + i][swc(tr + i, cb)];
      #pragma unroll
      for (int j = 0; j < 4; ++j) ka[j] = *(const float4*)&KsS[tc + j][swc(tc + j, cb)];
      #pragma unroll
      for (int i = 0; i < 4; ++i)
        #pragma unroll
        for (int j = 0; j < 4; ++j)
          s[i][j] += qa[i].x * ka[j].x + qa[i].y * ka[j].y +
                     qa[i].z * ka[j].z + qa[i].w * ka[j].w;
    }
    __syncthreads();  // all KsS reads done; safe to overwrite with P
    #pragma unroll
    for (int i = 0; i < 4; ++i) {
      float mt = fmaxf(fmaxf(s[i][0], s[i][1]), fmaxf(s[i][2], s[i][3]));
      #pragma unroll
      for (int msk = 1; msk < 16; msk <<= 1) mt = fmaxf(mt, __shfl_xor(mt, msk));
      float mn = fmaxf(m[i], mt);
      float sc = expf(m[i] - mn);
      float pr0 = expf(s[i][0] - mn), pr1 = expf(s[i][1] - mn);
      float pr2 = expf(s[i][2] - mn), pr3 = expf(s[i][3] - mn);
      float ts = pr0 + pr1 + pr2 + pr3;
      #pragma unroll
      for (int msk = 1; msk < 16; msk <<= 1) ts += __shfl_xor(ts, msk);
      l[i] = l[i] * sc + ts;
      m[i] = mn;
      acc[i][0] *= sc; acc[i][1] *= sc; acc[i][2] *= sc; acc[i][3] *= sc;
      float4 pv = make_float4(pr0, pr1, pr2, pr3);
      *(float4*)&KsS[tr + i][swc(tr + i, tc >> 2)] = pv;
    }
    __syncthreads();
    #pragma unroll
    for (int j4 = 0; j4 < 64; j4 += 4) {
      float4 pv[4], vv[4];
      #pragma unroll
      for (int i = 0; i < 4; ++i) pv[i] = *(const float4*)&KsS[tr + i][swc(tr + i, j4 >> 2)];
      #pragma unroll
      for (int u = 0; u < 4; ++u) vv[u] = *(const float4*)&VsS[j4 + u][swc(j4 + u, tc >> 2)];
      #pragma unroll
      for (int i = 0; i < 4; ++i) {
        acc[i][0] += pv[i].x * vv[0].x + pv[i].y * vv[1].x + pv[i].z * vv[2].x + pv[i].w * vv[3].x;
        acc[i][1] += pv[i].x * vv[0].y + pv[i].y * vv[1].y + pv[i].z * vv[2].y + pv[i].w * vv[3].y;
        acc[i][2] += pv[i].x * vv[0].z + pv[i].y * vv[1].z + pv[i].z * vv[2].z + pv[i].w * vv[3].z;
        acc[i][3] += pv[i].x * vv[0].w + pv[i].y * vv[1].w + pv[i].z * vv[2].w + pv[i].w * vv[3].w;
      }
    }
  }
  #pragma unroll
  for (int i = 0; i < 4; ++i) {
    float inv = 1.0f / l[i];
    float4 o = make_float4(acc[i][0] * inv, acc[i][1] * inv, acc[i][2] * inv, acc[i][3] * inv);
    *(float4*)&out[((size_t)b * 1024 + i0 + tr + i) * 512 + h * 64 + tc] = o;
  }
}

// ---------------------------------------------------------------------------
extern "C" void kernel_launch(void* const* d_in, const int* in_sizes, int n_in,
                              void* d_out, int out_size, void* d_ws, size_t ws_size,
                              hipStream_t stream) {
  const float* x     = (const float*)d_in[0];
  const float* q_w   = (const float*)d_in[1];
  const float* q_b   = (const float*)d_in[2];
  const float* k_w   = (const float*)d_in[3];
  const float* k_b   = (const float*)d_in[4];
  const float* v_w   = (const float*)d_in[5];
  const float* v_b   = (const float*)d_in[6];
  const float* o_w   = (const float*)d_in[7];
  const float* o_b   = (const float*)d_in[8];
  const float* dw_w  = (const float*)d_in[9];
  const float* dw_b  = (const float*)d_in[10];
  const float* off_w = (const float*)d_in[11];
  const float* btab  = (const float*)d_in[12];

  float* ws = (float*)d_ws;
  const size_t SZ = (size_t)4 * 1024 * 512;  // 2M floats
  float* Q    = ws;
  float* K    = ws + SZ;
  float* V    = ws + 2 * SZ;
  float* Ksb  = ws + 3 * SZ;
  float* Vsb  = ws + 4 * SZ;
  float* attn = ws + 5 * SZ;
  float* bias = ws + 6 * SZ;               // 1M floats
  float* samp = ws + 6 * SZ + 1048576;     // 65536 floats

  // bf16 split buffers (ushorts) after the fp32 region
  ushort* u = (ushort*)(ws + 7 * SZ);
  ushort* Xhi = u;               // 2M
  ushort* Xlo = u + 2097152;     // 2M
  ushort* Wq_h = u + 4194304;    // 256K each, 8 buffers
  ushort* Wq_l = Wq_h + 262144;
  ushort* Wk_h = Wq_h + 2 * 262144;
  ushort* Wk_l = Wq_h + 3 * 262144;
  ushort* Wv_h = Wq_h + 4 * 262144;
  ushort* Wv_l = Wq_h + 5 * 262144;
  ushort* Wo_h = Wq_h + 6 * 262144;
  ushort* Wo_l = Wq_h + 7 * 262144;
  // attn-output split aliases the K fp32 buffer (K dead after grid_sample)
  ushort* Aoh = (ushort*)(ws + SZ);
  ushort* Aol = Aoh + 2097152;

  split_kernel<<<2048, 256, 0, stream>>>(x, Xhi, Xlo, 524288);
  split_kernel<<<256, 256, 0, stream>>>(q_w, Wq_h, Wq_l, 65536);
  split_kernel<<<256, 256, 0, stream>>>(k_w, Wk_h, Wk_l, 65536);
  split_kernel<<<256, 256, 0, stream>>>(v_w, Wv_h, Wv_l, 65536);
  split_kernel<<<256, 256, 0, stream>>>(o_w, Wo_h, Wo_l, 65536);

  dim3 gg(8, 32);
  gemm_mfma<<<gg, 256, 0, stream>>>(Xhi, Xlo, Wq_h, Wq_l, q_b, Q);
  gemm_mfma<<<gg, 256, 0, stream>>>(Xhi, Xlo, Wk_h, Wk_l, k_b, K);
  gemm_mfma<<<gg, 256, 0, stream>>>(Xhi, Xlo, Wv_h, Wv_l, v_b, V);

  offset_net<<<4096, 512, 0, stream>>>(x, dw_w, dw_b, off_w, samp);
  grid_sample<<<dim3(256, 32), 256, 0, stream>>>(K, V, samp, Ksb, Vsb);
  bias_kernel<<<1024, 256, 0, stream>>>(btab, bias);
  attn_kernel<<<dim3(16, 32), 256, 0, stream>>>(Q, Ksb, Vsb, bias, attn);

  split_kernel<<<2048, 256, 0, stream>>>(attn, Aoh, Aol, 524288);
  gemm_mfma<<<gg, 256, 0, stream>>>(Aoh, Aol, Wo_h, Wo_l, o_b, (float*)d_out);
}

// Round 3
// 288.329 us; speedup vs baseline: 2.2766x; 2.0984x over previous
//
#include <hip/hip_runtime.h>
#include <math.h>

typedef unsigned short ushort;
typedef __attribute__((ext_vector_type(8))) short bf16x8;
typedef __attribute__((ext_vector_type(4))) float f32x4;

#define MFMA16(a, b, c) __builtin_amdgcn_mfma_f32_16x16x32_bf16(a, b, c, 0, 0, 0)
#define GLOAD16(g, l)                                                   \
  __builtin_amdgcn_global_load_lds(                                     \
      (const __attribute__((address_space(1))) unsigned int*)(g),       \
      (__attribute__((address_space(3))) unsigned int*)(l), 16, 0, 0)

__device__ __forceinline__ ushort f2bf(float f) {
  unsigned u = __float_as_uint(f);
  u += 0x7FFFu + ((u >> 16) & 1u);  // RNE
  return (ushort)(u >> 16);
}
__device__ __forceinline__ float bf2f(ushort b) {
  return __uint_as_float(((unsigned)b) << 16);
}

// ---------------------------------------------------------------------------
// Split fp32 -> (hi, lo) bf16 pair.  n4 = element_count/4.
// ---------------------------------------------------------------------------
__global__ __launch_bounds__(256) void split_kernel(
    const float* __restrict__ in, ushort* __restrict__ hi,
    ushort* __restrict__ lo, int n4) {
  int i = blockIdx.x * 256 + threadIdx.x;
  if (i >= n4) return;
  float4 v = ((const float4*)in)[i];
  ushort4 h, l;
  h.x = f2bf(v.x); l.x = f2bf(v.x - bf2f(h.x));
  h.y = f2bf(v.y); l.y = f2bf(v.y - bf2f(h.y));
  h.z = f2bf(v.z); l.z = f2bf(v.z - bf2f(h.z));
  h.w = f2bf(v.w); l.w = f2bf(v.w - bf2f(h.w));
  ((ushort4*)hi)[i] = h;
  ((ushort4*)lo)[i] = l;
}

// ---------------------------------------------------------------------------
// MFMA GEMM: Y[4096,512] = A[4096,512] @ W[512,512]^T + b, hi/lo split bf16.
// Tile 128x64, BK=64, 256 threads (4 waves 2x2), 16x16x32 MFMA, 3 passes.
// ---------------------------------------------------------------------------
__global__ __launch_bounds__(256) void gemm_mfma(
    const ushort* __restrict__ Ahi, const ushort* __restrict__ Alo,
    const ushort* __restrict__ Bhi, const ushort* __restrict__ Blo,
    const float* __restrict__ bias, float* __restrict__ Y) {
  __shared__ ushort lds[24576];
  ushort* sAhi = lds;
  ushort* sAlo = lds + 8192;
  ushort* sBhi = lds + 16384;
  ushort* sBlo = lds + 20480;
  int tid = threadIdx.x;
  int lane = tid & 63;
  int w = tid >> 6;
  int m0 = blockIdx.y * 128;
  int n0 = blockIdx.x * 64;
  int wr = (w >> 1) * 64;
  int wc = (w & 1) * 32;
  int l8r = lane >> 3;
  int sll = ((lane & 7) ^ l8r) << 3;
  int l16 = lane & 15, lq = lane >> 4;

  f32x4 acc[4][2];
  f32x4 zero = {0.f, 0.f, 0.f, 0.f};
  #pragma unroll
  for (int m = 0; m < 4; ++m)
    #pragma unroll
    for (int n = 0; n < 2; ++n) acc[m][n] = zero;

  for (int kt = 0; kt < 8; ++kt) {
    int kk = kt * 64;
    __syncthreads();
    #pragma unroll
    for (int q = 0; q < 4; ++q) {
      int ci = w * 4 + q;
      size_t go = (size_t)(m0 + ci * 8 + l8r) * 512 + kk + sll;
      GLOAD16(Ahi + go, sAhi + ci * 512);
      GLOAD16(Alo + go, sAlo + ci * 512);
    }
    #pragma unroll
    for (int q = 0; q < 2; ++q) {
      int ci = w * 2 + q;
      size_t go = (size_t)(n0 + ci * 8 + l8r) * 512 + kk + sll;
      GLOAD16(Bhi + go, sBhi + ci * 512);
      GLOAD16(Blo + go, sBlo + ci * 512);
    }
    __syncthreads();
    #pragma unroll
    for (int ks = 0; ks < 2; ++ks) {
      int slot = ks * 4 + lq;
      bf16x8 ah[4], al[4], bh[2], bl[2];
      #pragma unroll
      for (int m = 0; m < 4; ++m) {
        int r = wr + m * 16 + l16;
        int ph = (slot ^ (r & 7)) << 3;
        ah[m] = *(const bf16x8*)&sAhi[r * 64 + ph];
        al[m] = *(const bf16x8*)&sAlo[r * 64 + ph];
      }
      #pragma unroll
      for (int n = 0; n < 2; ++n) {
        int r = wc + n * 16 + l16;
        int ph = (slot ^ (r & 7)) << 3;
        bh[n] = *(const bf16x8*)&sBhi[r * 64 + ph];
        bl[n] = *(const bf16x8*)&sBlo[r * 64 + ph];
      }
      #pragma unroll
      for (int m = 0; m < 4; ++m)
        #pragma unroll
        for (int n = 0; n < 2; ++n) {
          acc[m][n] = MFMA16(ah[m], bh[n], acc[m][n]);
          acc[m][n] = MFMA16(ah[m], bl[n], acc[m][n]);
          acc[m][n] = MFMA16(al[m], bh[n], acc[m][n]);
        }
    }
  }
  #pragma unroll
  for (int n = 0; n < 2; ++n) {
    int col = n0 + wc + n * 16 + l16;
    float bv = bias[col];
    #pragma unroll
    for (int m = 0; m < 4; ++m) {
      #pragma unroll
      for (int j = 0; j < 4; ++j) {
        int row = m0 + wr + m * 16 + lq * 4 + j;
        Y[(size_t)row * 512 + col] = acc[m][n][j] + bv;
      }
    }
  }
}

// ---------------------------------------------------------------------------
// Offset network: depthwise 5x5 conv -> exact GELU -> 1x1(16) -> tanh*2 ->
// sample coords in pixel space.
// ---------------------------------------------------------------------------
__global__ __launch_bounds__(512) void offset_net(
    const float* __restrict__ x, const float* __restrict__ dw_w,
    const float* __restrict__ dw_b, const float* __restrict__ off_w,
    float* __restrict__ samp) {
  __shared__ float hbuf[512];
  __shared__ float obuf[16];
  int pix = blockIdx.x;
  int b = pix >> 10;
  int n = pix & 1023;
  int y = n >> 5, xx = n & 31;
  int c = threadIdx.x;
  float s = dw_b[c];
  #pragma unroll
  for (int ky = 0; ky < 5; ++ky) {
    int yy = y + ky - 2;
    if (yy < 0 || yy >= 32) continue;
    #pragma unroll
    for (int kx = 0; kx < 5; ++kx) {
      int xc = xx + kx - 2;
      if (xc < 0 || xc >= 32) continue;
      s += x[((size_t)b * 1024 + yy * 32 + xc) * 512 + c] * dw_w[c * 25 + ky * 5 + kx];
    }
  }
  float g = 0.5f * s * (1.0f + erff(s * 0.70710678118654752f));
  hbuf[c] = g;
  __syncthreads();
  int o = threadIdx.x >> 5;
  int lg = threadIdx.x & 31;
  float p = 0.f;
  for (int k = lg; k < 512; k += 32) p += hbuf[k] * off_w[o * 512 + k];
  #pragma unroll
  for (int m = 1; m < 32; m <<= 1) p += __shfl_xor(p, m);
  if (lg == 0) obuf[o] = tanhf(p) * 2.0f;
  __syncthreads();
  if (threadIdx.x < 8) {
    int h = threadIdx.x;
    float gx = -1.0f + 2.0f * (float)xx / 31.0f;
    float gy = -1.0f + 2.0f * (float)y / 31.0f;
    float sx = fminf(fmaxf(gx + obuf[2 * h], -1.0f), 1.0f);
    float sy = fminf(fmaxf(gy + obuf[2 * h + 1], -1.0f), 1.0f);
    float2 pc;
    pc.x = (sx + 1.0f) * 16.0f - 0.5f;
    pc.y = (sy + 1.0f) * 16.0f - 0.5f;
    ((float2*)samp)[(size_t)(b * 8 + h) * 1024 + n] = pc;
  }
}

// ---------------------------------------------------------------------------
// Bilinear grid-sample of K and V. Outputs: Ks hi/lo bf16 [bh][1024][64],
// Vt bf16 transposed [bh][64 d][1024 key]. Block = (jb, bh): 64 points.
// ---------------------------------------------------------------------------
__global__ __launch_bounds__(256) void grid_sample(
    const float* __restrict__ K, const float* __restrict__ V,
    const float* __restrict__ samp, ushort* __restrict__ Ksh,
    ushort* __restrict__ Ksl, ushort* __restrict__ Vt) {
  __shared__ ushort sV[64][72];
  int bh = blockIdx.y;
  int b = bh >> 3, h = bh & 7;
  int jb = blockIdx.x;
  int d = threadIdx.x & 63;
  for (int p = 0; p < 16; ++p) {
    int jl = p * 4 + (threadIdx.x >> 6);
    int j = jb * 64 + jl;
    float2 pc = ((const float2*)samp)[(size_t)bh * 1024 + j];
    float gx = pc.x, gy = pc.y;
    float x0 = floorf(gx), y0 = floorf(gy);
    float aK = 0.f, aV = 0.f;
    #pragma unroll
    for (int dy = 0; dy < 2; ++dy)
      #pragma unroll
      for (int dx = 0; dx < 2; ++dx) {
        float xi = x0 + (float)dx, yi = y0 + (float)dy;
        float wgt = (1.0f - fabsf(gx - xi)) * (1.0f - fabsf(gy - yi));
        if (xi >= 0.f && xi < 32.f && yi >= 0.f && yi < 32.f) {
          size_t base = ((size_t)b * 1024 + (int)yi * 32 + (int)xi) * 512 + h * 64 + d;
          aK += K[base] * wgt;
          aV += V[base] * wgt;
        }
      }
    ushort kh = f2bf(aK);
    size_t o = ((size_t)bh * 1024 + j) * 64 + d;
    Ksh[o] = kh;
    Ksl[o] = f2bf(aK - bf2f(kh));
    sV[jl][d] = f2bf(aV);
  }
  __syncthreads();
  int dd = threadIdx.x >> 2, c4 = threadIdx.x & 3;
  bf16x8 v0, v1;
  #pragma unroll
  for (int k = 0; k < 8; ++k) v0[k] = (short)sV[c4 * 16 + k][dd];
  #pragma unroll
  for (int k = 0; k < 8; ++k) v1[k] = (short)sV[c4 * 16 + 8 + k][dd];
  size_t o = ((size_t)bh * 64 + dd) * 1024 + jb * 64 + c4 * 16;
  *(bf16x8*)&Vt[o] = v0;
  *(bf16x8*)&Vt[o + 8] = v1;
}

// ---------------------------------------------------------------------------
// Relative-position bias via 4-tap bicubic along both axes.
// ---------------------------------------------------------------------------
__device__ __forceinline__ void bicubic_taps(int i, float* w, int* idx) {
  const float a = -0.75f;
  float src = ((float)i + 0.5f) * 0.0625f - 0.5f;
  float fi = floorf(src);
  int i0 = (int)fi;
  float t = src - fi;
  #pragma unroll
  for (int k = -1; k <= 2; ++k) {
    float d = fabsf(t - (float)k);
    float wv;
    if (d <= 1.0f)
      wv = ((a + 2.0f) * d - (a + 3.0f)) * d * d + 1.0f;
    else if (d < 2.0f)
      wv = a * (((d - 5.0f) * d + 8.0f) * d - 4.0f);
    else
      wv = 0.0f;
    int ic = i0 + k;
    ic = ic < 0 ? 0 : (ic > 63 ? 63 : ic);
    w[k + 1] = wv;
    idx[k + 1] = ic;
  }
}

__global__ __launch_bounds__(256) void bias_kernel(
    const float* __restrict__ table, float* __restrict__ bias) {
  __shared__ float tab[225];
  int i = blockIdx.x;
  int tid = threadIdx.x;
  if (tid < 225) tab[tid] = table[tid];
  __syncthreads();
  float wA[4]; int iA[4];
  bicubic_taps(i, wA, iA);
  for (int j = tid; j < 1024; j += 256) {
    float wB[4]; int iB[4];
    bicubic_taps(j, wB, iB);
    float sum = 0.f;
    #pragma unroll
    for (int ka = 0; ka < 4; ++ka) {
      int pa = iA[ka];
      int py = pa >> 3, px = pa & 7;
      float wa = wA[ka];
      #pragma unroll
      for (int kb = 0; kb < 4; ++kb) {
        int qb = iB[kb];
        int qy = qb >> 3, qx = qb & 7;
        sum += wa * wB[kb] * tab[(py - qy + 7) * 15 + (px - qx + 7)];
      }
    }
    bias[(size_t)i * 1024 + j] = sum;
  }
}

// ---------------------------------------------------------------------------
// MFMA flash attention. Block = 64 queries (4 waves x 16), loop 16 KV-tiles
// of 64 keys. QK^T: 3-pass hi/lo bf16; bias as MFMA C-init; online softmax
// in C-layout; PV: 1-pass bf16 via LDS P-tile and pre-transposed V.
// Output written directly as hi/lo bf16 for the final projection GEMM.
// ---------------------------------------------------------------------------
__global__ __launch_bounds__(256) void attn_mfma(
    const float* __restrict__ Q, const ushort* __restrict__ Kh,
    const ushort* __restrict__ Kl, const ushort* __restrict__ Vt,
    const float* __restrict__ bias, ushort* __restrict__ Oh,
    ushort* __restrict__ Ol) {
  __shared__ ushort lds[25088];
  ushort* sQh = lds;           // [64][64] swizzled
  ushort* sQl = lds + 4096;
  ushort* sKh = lds + 8192;
  ushort* sKl = lds + 12288;
  ushort* sVt = lds + 16384;   // [64 d][64 key] swizzled
  ushort* sP  = lds + 20480;   // per-wave [16][72]

  int tid = threadIdx.x;
  int lane = tid & 63;
  int w = tid >> 6;
  int l16 = lane & 15, lq = lane >> 4;
  int bh = blockIdx.y;
  int b = bh >> 3, h = bh & 7;
  int i0 = blockIdx.x * 64;

  // stage Q: fp32 -> (hi,lo) bf16, *0.125, chunk-swizzled
  {
    int row = tid >> 2;
    int c16 = tid & 3;
    const float* src = Q + ((size_t)b * 1024 + i0 + row) * 512 + h * 64 + c16 * 16;
    #pragma unroll
    for (int g = 0; g < 2; ++g) {
      bf16x8 hv, lv;
      #pragma unroll
      for (int u = 0; u < 8; ++u) {
        float f = src[g * 8 + u] * 0.125f;
        ushort hb = f2bf(f);
        hv[u] = (short)hb;
        lv[u] = (short)f2bf(f - bf2f(hb));
      }
      int slot = (c16 * 2 + g) ^ (row & 7);
      *(bf16x8*)&sQh[row * 64 + slot * 8] = hv;
      *(bf16x8*)&sQl[row * 64 + slot * 8] = lv;
    }
  }

  f32x4 oacc[4];
  f32x4 zero = {0.f, 0.f, 0.f, 0.f};
  #pragma unroll
  for (int n = 0; n < 4; ++n) oacc[n] = zero;
  float mrow[4], lrow[4];
  #pragma unroll
  for (int r = 0; r < 4; ++r) { mrow[r] = -INFINITY; lrow[r] = 0.f; }

  ushort* myP = sP + w * 1152;
  int r8 = lane >> 3, ch = lane & 7;

  for (int jt = 0; jt < 16; ++jt) {
    __syncthreads();
    #pragma unroll
    for (int q = 0; q < 2; ++q) {
      int row = w * 16 + q * 8 + r8;
      int gch = ch ^ (row & 7);
      size_t gk = ((size_t)bh * 1024 + jt * 64 + row) * 64 + gch * 8;
      GLOAD16(Kh + gk, sKh + (w * 16 + q * 8) * 64);
      GLOAD16(Kl + gk, sKl + (w * 16 + q * 8) * 64);
      size_t gv = ((size_t)bh * 64 + row) * 1024 + jt * 64 + gch * 8;
      GLOAD16(Vt + gv, sVt + (w * 16 + q * 8) * 64);
    }
    // bias -> score accumulator (C-layout: row = lq*4+r, col = l16)
    f32x4 sacc[4];
    #pragma unroll
    for (int n = 0; n < 4; ++n) {
      const float* bp = bias + (size_t)(i0 + w * 16 + lq * 4) * 1024 + jt * 64 + n * 16 + l16;
      #pragma unroll
      for (int r = 0; r < 4; ++r) sacc[n][r] = bp[(size_t)r * 1024];
    }
    __syncthreads();
    // QK^T, 3-pass hi/lo
    #pragma unroll
    for (int ks = 0; ks < 2; ++ks) {
      int cslot = ((ks * 4 + lq) ^ (l16 & 7)) * 8;
      int arow = (w * 16 + l16) * 64;
      bf16x8 aH = *(const bf16x8*)&sQh[arow + cslot];
      bf16x8 aL = *(const bf16x8*)&sQl[arow + cslot];
      #pragma unroll
      for (int n = 0; n < 4; ++n) {
        int brow = (n * 16 + l16) * 64;
        bf16x8 bH = *(const bf16x8*)&sKh[brow + cslot];
        bf16x8 bL = *(const bf16x8*)&sKl[brow + cslot];
        sacc[n] = MFMA16(aH, bH, sacc[n]);
        sacc[n] = MFMA16(aH, bL, sacc[n]);
        sacc[n] = MFMA16(aL, bH, sacc[n]);
      }
    }
    // online softmax; write P (bf16) to per-wave LDS tile
    #pragma unroll
    for (int r = 0; r < 4; ++r) {
      float mt = fmaxf(fmaxf(sacc[0][r], sacc[1][r]), fmaxf(sacc[2][r], sacc[3][r]));
      #pragma unroll
      for (int msk = 1; msk < 16; msk <<= 1) mt = fmaxf(mt, __shfl_xor(mt, msk));
      float mn = fmaxf(mrow[r], mt);
      float sc = __expf(mrow[r] - mn);
      float ts = 0.f;
      #pragma unroll
      for (int n = 0; n < 4; ++n) {
        float p = __expf(sacc[n][r] - mn);
        ts += p;
        myP[(lq * 4 + r) * 72 + n * 16 + l16] = f2bf(p);
      }
      #pragma unroll
      for (int msk = 1; msk < 16; msk <<= 1) ts += __shfl_xor(ts, msk);
      lrow[r] = lrow[r] * sc + ts;
      mrow[r] = mn;
      #pragma unroll
      for (int n = 0; n < 4; ++n) oacc[n][r] *= sc;
    }
    // PV: A = P [16q][64key], B = V^T [16d][64key]
    #pragma unroll
    for (int ks = 0; ks < 2; ++ks) {
      bf16x8 pa = *(const bf16x8*)&myP[l16 * 72 + (ks * 4 + lq) * 8];
      int cslot = ((ks * 4 + lq) ^ (l16 & 7)) * 8;
      #pragma unroll
      for (int n = 0; n < 4; ++n) {
        bf16x8 bv = *(const bf16x8*)&sVt[(n * 16 + l16) * 64 + cslot];
        oacc[n] = MFMA16(pa, bv, oacc[n]);
      }
    }
  }
  // epilogue: normalize, split hi/lo, store
  #pragma unroll
  for (int r = 0; r < 4; ++r) {
    float inv = 1.0f / lrow[r];
    int qr = i0 + w * 16 + lq * 4 + r;
    #pragma unroll
    for (int n = 0; n < 4; ++n) {
      float v = oacc[n][r] * inv;
      ushort hb = f2bf(v);
      size_t o = ((size_t)b * 1024 + qr) * 512 + h * 64 + n * 16 + l16;
      Oh[o] = hb;
      Ol[o] = f2bf(v - bf2f(hb));
    }
  }
}

// ---------------------------------------------------------------------------
extern "C" void kernel_launch(void* const* d_in, const int* in_sizes, int n_in,
                              void* d_out, int out_size, void* d_ws, size_t ws_size,
                              hipStream_t stream) {
  const float* x     = (const float*)d_in[0];
  const float* q_w   = (const float*)d_in[1];
  const float* q_b   = (const float*)d_in[2];
  const float* k_w   = (const float*)d_in[3];
  const float* k_b   = (const float*)d_in[4];
  const float* v_w   = (const float*)d_in[5];
  const float* v_b   = (const float*)d_in[6];
  const float* o_w   = (const float*)d_in[7];
  const float* o_b   = (const float*)d_in[8];
  const float* dw_w  = (const float*)d_in[9];
  const float* dw_b  = (const float*)d_in[10];
  const float* off_w = (const float*)d_in[11];
  const float* btab  = (const float*)d_in[12];

  float* ws = (float*)d_ws;
  const size_t SZ = (size_t)4 * 1024 * 512;  // 2M elements
  float* Q    = ws;
  float* K    = ws + SZ;
  float* V    = ws + 2 * SZ;
  float* bias = ws + 3 * SZ;                 // 1M floats
  float* samp = ws + 3 * SZ + 1048576;       // 65536 floats

  ushort* u = (ushort*)(samp + 65536);
  ushort* Xhi  = u;                          // 2M each
  ushort* Xlo  = Xhi + SZ;
  ushort* Wq_h = Xlo + SZ;                   // 256K each, 8 buffers
  ushort* Wq_l = Wq_h + 262144;
  ushort* Wk_h = Wq_h + 2 * 262144;
  ushort* Wk_l = Wq_h + 3 * 262144;
  ushort* Wv_h = Wq_h + 4 * 262144;
  ushort* Wv_l = Wq_h + 5 * 262144;
  ushort* Wo_h = Wq_h + 6 * 262144;
  ushort* Wo_l = Wq_h + 7 * 262144;
  ushort* Ksh  = Wq_h + 8 * 262144;          // 2M each
  ushort* Ksl  = Ksh + SZ;
  ushort* Vtr  = Ksl + SZ;
  ushort* Aoh  = Vtr + SZ;
  ushort* Aol  = Aoh + SZ;

  split_kernel<<<2048, 256, 0, stream>>>(x, Xhi, Xlo, 524288);
  split_kernel<<<256, 256, 0, stream>>>(q_w, Wq_h, Wq_l, 65536);
  split_kernel<<<256, 256, 0, stream>>>(k_w, Wk_h, Wk_l, 65536);
  split_kernel<<<256, 256, 0, stream>>>(v_w, Wv_h, Wv_l, 65536);
  split_kernel<<<256, 256, 0, stream>>>(o_w, Wo_h, Wo_l, 65536);

  dim3 gg(8, 32);
  gemm_mfma<<<gg, 256, 0, stream>>>(Xhi, Xlo, Wq_h, Wq_l, q_b, Q);
  gemm_mfma<<<gg, 256, 0, stream>>>(Xhi, Xlo, Wk_h, Wk_l, k_b, K);
  gemm_mfma<<<gg, 256, 0, stream>>>(Xhi, Xlo, Wv_h, Wv_l, v_b, V);

  offset_net<<<4096, 512, 0, stream>>>(x, dw_w, dw_b, off_w, samp);
  bias_kernel<<<1024, 256, 0, stream>>>(btab, bias);
  grid_sample<<<dim3(16, 32), 256, 0, stream>>>(K, V, samp, Ksh, Ksl, Vtr);

  attn_mfma<<<dim3(16, 32), 256, 0, stream>>>(Q, Ksh, Ksl, Vtr, bias, Aoh, Aol);

  gemm_mfma<<<gg, 256, 0, stream>>>(Aoh, Aol, Wo_h, Wo_l, o_b, (float*)d_out);
}

// Round 4
// 190.666 us; speedup vs baseline: 3.4427x; 1.5122x over previous
//
#include <hip/hip_runtime.h>
#include <math.h>

typedef unsigned short ushort;
typedef __attribute__((ext_vector_type(8))) short bf16x8;
typedef __attribute__((ext_vector_type(4))) float f32x4;

#define MFMA16(a, b, c) __builtin_amdgcn_mfma_f32_16x16x32_bf16(a, b, c, 0, 0, 0)
#define GLOAD16(g, l)                                                   \
  __builtin_amdgcn_global_load_lds(                                     \
      (const __attribute__((address_space(1))) unsigned int*)(g),       \
      (__attribute__((address_space(3))) unsigned int*)(l), 16, 0, 0)

__device__ __forceinline__ ushort f2bf(float f) {
  unsigned u = __float_as_uint(f);
  u += 0x7FFFu + ((u >> 16) & 1u);  // RNE
  return (ushort)(u >> 16);
}
__device__ __forceinline__ float bf2f(ushort b) {
  return __uint_as_float(((unsigned)b) << 16);
}

// ---------------------------------------------------------------------------
// Split fp32 -> (hi, lo) bf16 pair.  n4 = element_count/4.
// ---------------------------------------------------------------------------
__global__ __launch_bounds__(256) void split_kernel(
    const float* __restrict__ in, ushort* __restrict__ hi,
    ushort* __restrict__ lo, int n4) {
  int i = blockIdx.x * 256 + threadIdx.x;
  if (i >= n4) return;
  float4 v = ((const float4*)in)[i];
  ushort4 h, l;
  h.x = f2bf(v.x); l.x = f2bf(v.x - bf2f(h.x));
  h.y = f2bf(v.y); l.y = f2bf(v.y - bf2f(h.y));
  h.z = f2bf(v.z); l.z = f2bf(v.z - bf2f(h.z));
  h.w = f2bf(v.w); l.w = f2bf(v.w - bf2f(h.w));
  ((ushort4*)hi)[i] = h;
  ((ushort4*)lo)[i] = l;
}

// ---------------------------------------------------------------------------
// MFMA GEMM: Y[4096,512] = A[4096,512] @ W[512,512]^T + b, hi/lo split bf16.
// ---------------------------------------------------------------------------
__global__ __launch_bounds__(256) void gemm_mfma(
    const ushort* __restrict__ Ahi, const ushort* __restrict__ Alo,
    const ushort* __restrict__ Bhi, const ushort* __restrict__ Blo,
    const float* __restrict__ bias, float* __restrict__ Y) {
  __shared__ ushort lds[24576];
  ushort* sAhi = lds;
  ushort* sAlo = lds + 8192;
  ushort* sBhi = lds + 16384;
  ushort* sBlo = lds + 20480;
  int tid = threadIdx.x;
  int lane = tid & 63;
  int w = tid >> 6;
  int m0 = blockIdx.y * 128;
  int n0 = blockIdx.x * 64;
  int wr = (w >> 1) * 64;
  int wc = (w & 1) * 32;
  int l8r = lane >> 3;
  int sll = ((lane & 7) ^ l8r) << 3;
  int l16 = lane & 15, lq = lane >> 4;

  f32x4 acc[4][2];
  f32x4 zero = {0.f, 0.f, 0.f, 0.f};
  #pragma unroll
  for (int m = 0; m < 4; ++m)
    #pragma unroll
    for (int n = 0; n < 2; ++n) acc[m][n] = zero;

  for (int kt = 0; kt < 8; ++kt) {
    int kk = kt * 64;
    __syncthreads();
    #pragma unroll
    for (int q = 0; q < 4; ++q) {
      int ci = w * 4 + q;
      size_t go = (size_t)(m0 + ci * 8 + l8r) * 512 + kk + sll;
      GLOAD16(Ahi + go, sAhi + ci * 512);
      GLOAD16(Alo + go, sAlo + ci * 512);
    }
    #pragma unroll
    for (int q = 0; q < 2; ++q) {
      int ci = w * 2 + q;
      size_t go = (size_t)(n0 + ci * 8 + l8r) * 512 + kk + sll;
      GLOAD16(Bhi + go, sBhi + ci * 512);
      GLOAD16(Blo + go, sBlo + ci * 512);
    }
    __syncthreads();
    #pragma unroll
    for (int ks = 0; ks < 2; ++ks) {
      int slot = ks * 4 + lq;
      bf16x8 ah[4], al[4], bh[2], bl[2];
      #pragma unroll
      for (int m = 0; m < 4; ++m) {
        int r = wr + m * 16 + l16;
        int ph = (slot ^ (r & 7)) << 3;
        ah[m] = *(const bf16x8*)&sAhi[r * 64 + ph];
        al[m] = *(const bf16x8*)&sAlo[r * 64 + ph];
      }
      #pragma unroll
      for (int n = 0; n < 2; ++n) {
        int r = wc + n * 16 + l16;
        int ph = (slot ^ (r & 7)) << 3;
        bh[n] = *(const bf16x8*)&sBhi[r * 64 + ph];
        bl[n] = *(const bf16x8*)&sBlo[r * 64 + ph];
      }
      #pragma unroll
      for (int m = 0; m < 4; ++m)
        #pragma unroll
        for (int n = 0; n < 2; ++n) {
          acc[m][n] = MFMA16(ah[m], bh[n], acc[m][n]);
          acc[m][n] = MFMA16(ah[m], bl[n], acc[m][n]);
          acc[m][n] = MFMA16(al[m], bh[n], acc[m][n]);
        }
    }
  }
  #pragma unroll
  for (int n = 0; n < 2; ++n) {
    int col = n0 + wc + n * 16 + l16;
    float bv = bias[col];
    #pragma unroll
    for (int m = 0; m < 4; ++m) {
      #pragma unroll
      for (int j = 0; j < 4; ++j) {
        int row = m0 + wr + m * 16 + lq * 4 + j;
        Y[(size_t)row * 512 + col] = acc[m][n][j] + bv;
      }
    }
  }
}

// ---------------------------------------------------------------------------
// Transpose depthwise weights [512][25] -> [25][512] for coalesced loads.
// ---------------------------------------------------------------------------
__global__ __launch_bounds__(256) void dw_transpose(
    const float* __restrict__ dw, float* __restrict__ dwT) {
  int c = blockIdx.x * 256 + threadIdx.x;
  #pragma unroll
  for (int k = 0; k < 25; ++k) dwT[k * 512 + c] = dw[c * 25 + k];
}

// ---------------------------------------------------------------------------
// Offset network v2. Block = (half-row of 16 px, y, b); 256 threads.
// Phase 1: thread = 2-channel unit; 5x5 depthwise conv via register sliding
//   window (5 float2 loads/pixel) + GELU -> h in LDS.
// Phase 2: thread = (px,o): 512-dot from LDS -> tanh*2 -> coords -> samp.
// ---------------------------------------------------------------------------
__global__ __launch_bounds__(256) void offset_net2(
    const float* __restrict__ x, const float* __restrict__ dwT,
    const float* __restrict__ dw_b, const float* __restrict__ off_w,
    float* __restrict__ samp) {
  __shared__ float wT[16][516];
  __shared__ float hT[16][516];
  __shared__ float ofs[16][16];
  int x0 = blockIdx.x * 16;
  int y = blockIdx.y;
  int b = blockIdx.z;
  int tid = threadIdx.x;

  // stage off_w [16][512] into LDS (pad 516)
  for (int e = tid; e < 2048; e += 256) {
    int o = e >> 7, c4 = e & 127;
    *(float4*)&wT[o][c4 * 4] = *(const float4*)&off_w[o * 512 + c4 * 4];
  }

  // ---- phase 1: depthwise conv, sliding window ----
  int c = tid * 2;
  float2 dwv[25];
  #pragma unroll
  for (int k = 0; k < 25; ++k) dwv[k] = *(const float2*)&dwT[k * 512 + c];
  float2 cb = *(const float2*)&dw_b[c];

  const float* xb = x + (size_t)b * 1024 * 512 + c;
  bool rv[5];
  #pragma unroll
  for (int r = 0; r < 5; ++r) {
    int yy = y - 2 + r;
    rv[r] = (yy >= 0 && yy < 32);
  }
  float2 win[5][5];
  #pragma unroll
  for (int j = 0; j < 4; ++j) {
    int xc = x0 - 2 + j;
    bool cvld = (xc >= 0 && xc < 32);
    #pragma unroll
    for (int r = 0; r < 5; ++r) {
      win[r][j] = (rv[r] && cvld)
          ? *(const float2*)&xb[(size_t)((y - 2 + r) * 32 + xc) * 512]
          : make_float2(0.f, 0.f);
    }
  }
  #pragma unroll
  for (int i = 0; i < 16; ++i) {
    int xc = x0 + i + 2;
    bool cvld = (xc < 32);
    #pragma unroll
    for (int r = 0; r < 5; ++r) {
      win[r][4] = (rv[r] && cvld)
          ? *(const float2*)&xb[(size_t)((y - 2 + r) * 32 + xc) * 512]
          : make_float2(0.f, 0.f);
    }
    float sx = cb.x, sy = cb.y;
    #pragma unroll
    for (int r = 0; r < 5; ++r)
      #pragma unroll
      for (int j = 0; j < 5; ++j) {
        sx += win[r][j].x * dwv[r * 5 + j].x;
        sy += win[r][j].y * dwv[r * 5 + j].y;
      }
    float g0 = 0.5f * sx * (1.0f + erff(sx * 0.70710678118654752f));
    float g1 = 0.5f * sy * (1.0f + erff(sy * 0.70710678118654752f));
    *(float2*)&hT[i][c] = make_float2(g0, g1);
    #pragma unroll
    for (int r = 0; r < 5; ++r) {
      win[r][0] = win[r][1]; win[r][1] = win[r][2];
      win[r][2] = win[r][3]; win[r][3] = win[r][4];
    }
  }
  __syncthreads();

  // ---- phase 2: 1x1 matvec (16 outputs) ----
  {
    int o = tid & 15, px = tid >> 4;
    float acc = 0.f;
    #pragma unroll 4
    for (int c4 = 0; c4 < 128; ++c4) {
      float4 hv = *(const float4*)&hT[px][c4 * 4];
      float4 wv = *(const float4*)&wT[o][c4 * 4];
      acc += hv.x * wv.x + hv.y * wv.y + hv.z * wv.z + hv.w * wv.w;
    }
    ofs[px][o] = tanhf(acc) * 2.0f;
  }
  __syncthreads();

  // ---- phase 3: coords ----
  if (tid < 128) {
    int px = tid >> 3, h = tid & 7;
    int n = y * 32 + x0 + px;
    float gx = -1.0f + 2.0f * (float)(x0 + px) / 31.0f;
    float gy = -1.0f + 2.0f * (float)y / 31.0f;
    float sx = fminf(fmaxf(gx + ofs[px][2 * h], -1.0f), 1.0f);
    float sy = fminf(fmaxf(gy + ofs[px][2 * h + 1], -1.0f), 1.0f);
    float2 pc;
    pc.x = (sx + 1.0f) * 16.0f - 0.5f;
    pc.y = (sy + 1.0f) * 16.0f - 0.5f;
    ((float2*)samp)[(size_t)(b * 8 + h) * 1024 + n] = pc;
  }
}

// ---------------------------------------------------------------------------
// Bilinear grid-sample of K and V. Outputs: Ks hi/lo bf16 [bh][1024][64],
// Vt bf16 transposed [bh][64 d][1024 key].
// ---------------------------------------------------------------------------
__global__ __launch_bounds__(256) void grid_sample(
    const float* __restrict__ K, const float* __restrict__ V,
    const float* __restrict__ samp, ushort* __restrict__ Ksh,
    ushort* __restrict__ Ksl, ushort* __restrict__ Vt) {
  __shared__ ushort sV[64][72];
  int bh = blockIdx.y;
  int b = bh >> 3, h = bh & 7;
  int jb = blockIdx.x;
  int d = threadIdx.x & 63;
  for (int p = 0; p < 16; ++p) {
    int jl = p * 4 + (threadIdx.x >> 6);
    int j = jb * 64 + jl;
    float2 pc = ((const float2*)samp)[(size_t)bh * 1024 + j];
    float gx = pc.x, gy = pc.y;
    float x0 = floorf(gx), y0 = floorf(gy);
    float aK = 0.f, aV = 0.f;
    #pragma unroll
    for (int dy = 0; dy < 2; ++dy)
      #pragma unroll
      for (int dx = 0; dx < 2; ++dx) {
        float xi = x0 + (float)dx, yi = y0 + (float)dy;
        float wgt = (1.0f - fabsf(gx - xi)) * (1.0f - fabsf(gy - yi));
        if (xi >= 0.f && xi < 32.f && yi >= 0.f && yi < 32.f) {
          size_t base = ((size_t)b * 1024 + (int)yi * 32 + (int)xi) * 512 + h * 64 + d;
          aK += K[base] * wgt;
          aV += V[base] * wgt;
        }
      }
    ushort kh = f2bf(aK);
    size_t o = ((size_t)bh * 1024 + j) * 64 + d;
    Ksh[o] = kh;
    Ksl[o] = f2bf(aK - bf2f(kh));
    sV[jl][d] = f2bf(aV);
  }
  __syncthreads();
  int dd = threadIdx.x >> 2, c4 = threadIdx.x & 3;
  bf16x8 v0, v1;
  #pragma unroll
  for (int k = 0; k < 8; ++k) v0[k] = (short)sV[c4 * 16 + k][dd];
  #pragma unroll
  for (int k = 0; k < 8; ++k) v1[k] = (short)sV[c4 * 16 + 8 + k][dd];
  size_t o = ((size_t)bh * 64 + dd) * 1024 + jb * 64 + c4 * 16;
  *(bf16x8*)&Vt[o] = v0;
  *(bf16x8*)&Vt[o + 8] = v1;
}

// ---------------------------------------------------------------------------
// Relative-position bias via 4-tap bicubic along both axes.
// ---------------------------------------------------------------------------
__device__ __forceinline__ void bicubic_taps(int i, float* w, int* idx) {
  const float a = -0.75f;
  float src = ((float)i + 0.5f) * 0.0625f - 0.5f;
  float fi = floorf(src);
  int i0 = (int)fi;
  float t = src - fi;
  #pragma unroll
  for (int k = -1; k <= 2; ++k) {
    float d = fabsf(t - (float)k);
    float wv;
    if (d <= 1.0f)
      wv = ((a + 2.0f) * d - (a + 3.0f)) * d * d + 1.0f;
    else if (d < 2.0f)
      wv = a * (((d - 5.0f) * d + 8.0f) * d - 4.0f);
    else
      wv = 0.0f;
    int ic = i0 + k;
    ic = ic < 0 ? 0 : (ic > 63 ? 63 : ic);
    w[k + 1] = wv;
    idx[k + 1] = ic;
  }
}

__global__ __launch_bounds__(256) void bias_kernel(
    const float* __restrict__ table, float* __restrict__ bias) {
  __shared__ float tab[225];
  int i = blockIdx.x;
  int tid = threadIdx.x;
  if (tid < 225) tab[tid] = table[tid];
  __syncthreads();
  float wA[4]; int iA[4];
  bicubic_taps(i, wA, iA);
  for (int j = tid; j < 1024; j += 256) {
    float wB[4]; int iB[4];
    bicubic_taps(j, wB, iB);
    float sum = 0.f;
    #pragma unroll
    for (int ka = 0; ka < 4; ++ka) {
      int pa = iA[ka];
      int py = pa >> 3, px = pa & 7;
      float wa = wA[ka];
      #pragma unroll
      for (int kb = 0; kb < 4; ++kb) {
        int qb = iB[kb];
        int qy = qb >> 3, qx = qb & 7;
        sum += wa * wB[kb] * tab[(py - qy + 7) * 15 + (px - qx + 7)];
      }
    }
    bias[(size_t)i * 1024 + j] = sum;
  }
}

// ---------------------------------------------------------------------------
// MFMA flash attention (as round 3).
// ---------------------------------------------------------------------------
__global__ __launch_bounds__(256) void attn_mfma(
    const float* __restrict__ Q, const ushort* __restrict__ Kh,
    const ushort* __restrict__ Kl, const ushort* __restrict__ Vt,
    const float* __restrict__ bias, ushort* __restrict__ Oh,
    ushort* __restrict__ Ol) {
  __shared__ ushort lds[25088];
  ushort* sQh = lds;
  ushort* sQl = lds + 4096;
  ushort* sKh = lds + 8192;
  ushort* sKl = lds + 12288;
  ushort* sVt = lds + 16384;
  ushort* sP  = lds + 20480;

  int tid = threadIdx.x;
  int lane = tid & 63;
  int w = tid >> 6;
  int l16 = lane & 15, lq = lane >> 4;
  int bh = blockIdx.y;
  int b = bh >> 3, h = bh & 7;
  int i0 = blockIdx.x * 64;

  {
    int row = tid >> 2;
    int c16 = tid & 3;
    const float* src = Q + ((size_t)b * 1024 + i0 + row) * 512 + h * 64 + c16 * 16;
    #pragma unroll
    for (int g = 0; g < 2; ++g) {
      bf16x8 hv, lv;
      #pragma unroll
      for (int u = 0; u < 8; ++u) {
        float f = src[g * 8 + u] * 0.125f;
        ushort hb = f2bf(f);
        hv[u] = (short)hb;
        lv[u] = (short)f2bf(f - bf2f(hb));
      }
      int slot = (c16 * 2 + g) ^ (row & 7);
      *(bf16x8*)&sQh[row * 64 + slot * 8] = hv;
      *(bf16x8*)&sQl[row * 64 + slot * 8] = lv;
    }
  }

  f32x4 oacc[4];
  f32x4 zero = {0.f, 0.f, 0.f, 0.f};
  #pragma unroll
  for (int n = 0; n < 4; ++n) oacc[n] = zero;
  float mrow[4], lrow[4];
  #pragma unroll
  for (int r = 0; r < 4; ++r) { mrow[r] = -INFINITY; lrow[r] = 0.f; }

  ushort* myP = sP + w * 1152;
  int r8 = lane >> 3, ch = lane & 7;

  for (int jt = 0; jt < 16; ++jt) {
    __syncthreads();
    #pragma unroll
    for (int q = 0; q < 2; ++q) {
      int row = w * 16 + q * 8 + r8;
      int gch = ch ^ (row & 7);
      size_t gk = ((size_t)bh * 1024 + jt * 64 + row) * 64 + gch * 8;
      GLOAD16(Kh + gk, sKh + (w * 16 + q * 8) * 64);
      GLOAD16(Kl + gk, sKl + (w * 16 + q * 8) * 64);
      size_t gv = ((size_t)bh * 64 + row) * 1024 + jt * 64 + gch * 8;
      GLOAD16(Vt + gv, sVt + (w * 16 + q * 8) * 64);
    }
    f32x4 sacc[4];
    #pragma unroll
    for (int n = 0; n < 4; ++n) {
      const float* bp = bias + (size_t)(i0 + w * 16 + lq * 4) * 1024 + jt * 64 + n * 16 + l16;
      #pragma unroll
      for (int r = 0; r < 4; ++r) sacc[n][r] = bp[(size_t)r * 1024];
    }
    __syncthreads();
    #pragma unroll
    for (int ks = 0; ks < 2; ++ks) {
      int cslot = ((ks * 4 + lq) ^ (l16 & 7)) * 8;
      int arow = (w * 16 + l16) * 64;
      bf16x8 aH = *(const bf16x8*)&sQh[arow + cslot];
      bf16x8 aL = *(const bf16x8*)&sQl[arow + cslot];
      #pragma unroll
      for (int n = 0; n < 4; ++n) {
        int brow = (n * 16 + l16) * 64;
        bf16x8 bH = *(const bf16x8*)&sKh[brow + cslot];
        bf16x8 bL = *(const bf16x8*)&sKl[brow + cslot];
        sacc[n] = MFMA16(aH, bH, sacc[n]);
        sacc[n] = MFMA16(aH, bL, sacc[n]);
        sacc[n] = MFMA16(aL, bH, sacc[n]);
      }
    }
    #pragma unroll
    for (int r = 0; r < 4; ++r) {
      float mt = fmaxf(fmaxf(sacc[0][r], sacc[1][r]), fmaxf(sacc[2][r], sacc[3][r]));
      #pragma unroll
      for (int msk = 1; msk < 16; msk <<= 1) mt = fmaxf(mt, __shfl_xor(mt, msk));
      float mn = fmaxf(mrow[r], mt);
      float sc = __expf(mrow[r] - mn);
      float ts = 0.f;
      #pragma unroll
      for (int n = 0; n < 4; ++n) {
        float p = __expf(sacc[n][r] - mn);
        ts += p;
        myP[(lq * 4 + r) * 72 + n * 16 + l16] = f2bf(p);
      }
      #pragma unroll
      for (int msk = 1; msk < 16; msk <<= 1) ts += __shfl_xor(ts, msk);
      lrow[r] = lrow[r] * sc + ts;
      mrow[r] = mn;
      #pragma unroll
      for (int n = 0; n < 4; ++n) oacc[n][r] *= sc;
    }
    #pragma unroll
    for (int ks = 0; ks < 2; ++ks) {
      bf16x8 pa = *(const bf16x8*)&myP[l16 * 72 + (ks * 4 + lq) * 8];
      int cslot = ((ks * 4 + lq) ^ (l16 & 7)) * 8;
      #pragma unroll
      for (int n = 0; n < 4; ++n) {
        bf16x8 bv = *(const bf16x8*)&sVt[(n * 16 + l16) * 64 + cslot];
        oacc[n] = MFMA16(pa, bv, oacc[n]);
      }
    }
  }
  #pragma unroll
  for (int r = 0; r < 4; ++r) {
    float inv = 1.0f / lrow[r];
    int qr = i0 + w * 16 + lq * 4 + r;
    #pragma unroll
    for (int n = 0; n < 4; ++n) {
      float v = oacc[n][r] * inv;
      ushort hb = f2bf(v);
      size_t o = ((size_t)b * 1024 + qr) * 512 + h * 64 + n * 16 + l16;
      Oh[o] = hb;
      Ol[o] = f2bf(v - bf2f(hb));
    }
  }
}

// ---------------------------------------------------------------------------
extern "C" void kernel_launch(void* const* d_in, const int* in_sizes, int n_in,
                              void* d_out, int out_size, void* d_ws, size_t ws_size,
                              hipStream_t stream) {
  const float* x     = (const float*)d_in[0];
  const float* q_w   = (const float*)d_in[1];
  const float* q_b   = (const float*)d_in[2];
  const float* k_w   = (const float*)d_in[3];
  const float* k_b   = (const float*)d_in[4];
  const float* v_w   = (const float*)d_in[5];
  const float* v_b   = (const float*)d_in[6];
  const float* o_w   = (const float*)d_in[7];
  const float* o_b   = (const float*)d_in[8];
  const float* dw_w  = (const float*)d_in[9];
  const float* dw_b  = (const float*)d_in[10];
  const float* off_w = (const float*)d_in[11];
  const float* btab  = (const float*)d_in[12];

  float* ws = (float*)d_ws;
  const size_t SZ = (size_t)4 * 1024 * 512;  // 2M elements
  float* Q    = ws;
  float* K    = ws + SZ;
  float* V    = ws + 2 * SZ;
  float* bias = ws + 3 * SZ;                 // 1M floats
  float* samp = ws + 3 * SZ + 1048576;       // 65536 floats

  ushort* u = (ushort*)(samp + 65536);
  ushort* Xhi  = u;                          // 2M each
  ushort* Xlo  = Xhi + SZ;
  ushort* Wq_h = Xlo + SZ;                   // 256K each, 8 buffers
  ushort* Wq_l = Wq_h + 262144;
  ushort* Wk_h = Wq_h + 2 * 262144;
  ushort* Wk_l = Wq_h + 3 * 262144;
  ushort* Wv_h = Wq_h + 4 * 262144;
  ushort* Wv_l = Wq_h + 5 * 262144;
  ushort* Wo_h = Wq_h + 6 * 262144;
  ushort* Wo_l = Wq_h + 7 * 262144;
  ushort* Ksh  = Wq_h + 8 * 262144;          // 2M each
  ushort* Ksl  = Ksh + SZ;
  ushort* Vtr  = Ksl + SZ;
  ushort* Aoh  = Vtr + SZ;
  ushort* Aol  = Aoh + SZ;
  float* dwT   = (float*)(Aol + SZ);         // 25*512 floats

  split_kernel<<<2048, 256, 0, stream>>>(x, Xhi, Xlo, 524288);
  split_kernel<<<256, 256, 0, stream>>>(q_w, Wq_h, Wq_l, 65536);
  split_kernel<<<256, 256, 0, stream>>>(k_w, Wk_h, Wk_l, 65536);
  split_kernel<<<256, 256, 0, stream>>>(v_w, Wv_h, Wv_l, 65536);
  split_kernel<<<256, 256, 0, stream>>>(o_w, Wo_h, Wo_l, 65536);
  dw_transpose<<<2, 256, 0, stream>>>(dw_w, dwT);

  dim3 gg(8, 32);
  gemm_mfma<<<gg, 256, 0, stream>>>(Xhi, Xlo, Wq_h, Wq_l, q_b, Q);
  gemm_mfma<<<gg, 256, 0, stream>>>(Xhi, Xlo, Wk_h, Wk_l, k_b, K);
  gemm_mfma<<<gg, 256, 0, stream>>>(Xhi, Xlo, Wv_h, Wv_l, v_b, V);

  offset_net2<<<dim3(2, 32, 4), 256, 0, stream>>>(x, dwT, dw_b, off_w, samp);
  bias_kernel<<<1024, 256, 0, stream>>>(btab, bias);
  grid_sample<<<dim3(16, 32), 256, 0, stream>>>(K, V, samp, Ksh, Ksl, Vtr);

  attn_mfma<<<dim3(16, 32), 256, 0, stream>>>(Q, Ksh, Ksl, Vtr, bias, Aoh, Aol);

  gemm_mfma<<<gg, 256, 0, stream>>>(Aoh, Aol, Wo_h, Wo_l, o_b, (float*)d_out);
}

// Round 5
// 152.917 us; speedup vs baseline: 4.2926x; 1.2469x over previous
//
#include <hip/hip_runtime.h>
#include <math.h>

typedef unsigned short ushort;
typedef __attribute__((ext_vector_type(8))) short bf16x8;
typedef __attribute__((ext_vector_type(4))) float f32x4;

#define MFMA16(a, b, c) __builtin_amdgcn_mfma_f32_16x16x32_bf16(a, b, c, 0, 0, 0)
#define GLOAD16(g, l)                                                   \
  __builtin_amdgcn_global_load_lds(                                     \
      (const __attribute__((address_space(1))) unsigned int*)(g),       \
      (__attribute__((address_space(3))) unsigned int*)(l), 16, 0, 0)

__device__ __forceinline__ ushort f2bf(float f) {
  unsigned u = __float_as_uint(f);
  u += 0x7FFFu + ((u >> 16) & 1u);  // RNE
  return (ushort)(u >> 16);
}
__device__ __forceinline__ float bf2f(ushort b) {
  return __uint_as_float(((unsigned)b) << 16);
}

// ---------------------------------------------------------------------------
// Split fp32 -> (hi, lo) bf16 pair.  n4 = element_count/4.
// ---------------------------------------------------------------------------
__global__ __launch_bounds__(256) void split_kernel(
    const float* __restrict__ in, ushort* __restrict__ hi,
    ushort* __restrict__ lo, int n4) {
  int i = blockIdx.x * 256 + threadIdx.x;
  if (i >= n4) return;
  float4 v = ((const float4*)in)[i];
  ushort4 h, l;
  h.x = f2bf(v.x); l.x = f2bf(v.x - bf2f(h.x));
  h.y = f2bf(v.y); l.y = f2bf(v.y - bf2f(h.y));
  h.z = f2bf(v.z); l.z = f2bf(v.z - bf2f(h.z));
  h.w = f2bf(v.w); l.w = f2bf(v.w - bf2f(h.w));
  ((ushort4*)hi)[i] = h;
  ((ushort4*)lo)[i] = l;
}

// ---------------------------------------------------------------------------
// Fused weight prep: 4 weight splits (hi/lo bf16) + dw transpose, one launch.
// ---------------------------------------------------------------------------
__global__ __launch_bounds__(256) void prep_weights(
    const float* __restrict__ q_w, const float* __restrict__ k_w,
    const float* __restrict__ v_w, const float* __restrict__ o_w,
    const float* __restrict__ dw_w, ushort* __restrict__ Wqh,
    ushort* __restrict__ Wql, ushort* __restrict__ Wkh,
    ushort* __restrict__ Wkl, ushort* __restrict__ Wvh,
    ushort* __restrict__ Wvl, ushort* __restrict__ Woh,
    ushort* __restrict__ Wol, float* __restrict__ dwT) {
  int blk = blockIdx.x;
  if (blk < 1024) {
    int grp = blk >> 8;
    const float* in = grp == 0 ? q_w : grp == 1 ? k_w : grp == 2 ? v_w : o_w;
    ushort* hi = grp == 0 ? Wqh : grp == 1 ? Wkh : grp == 2 ? Wvh : Woh;
    ushort* lo = grp == 0 ? Wql : grp == 1 ? Wkl : grp == 2 ? Wvl : Wol;
    int i = (blk & 255) * 256 + threadIdx.x;
    float4 v = ((const float4*)in)[i];
    ushort4 h, l;
    h.x = f2bf(v.x); l.x = f2bf(v.x - bf2f(h.x));
    h.y = f2bf(v.y); l.y = f2bf(v.y - bf2f(h.y));
    h.z = f2bf(v.z); l.z = f2bf(v.z - bf2f(h.z));
    h.w = f2bf(v.w); l.w = f2bf(v.w - bf2f(h.w));
    ((ushort4*)hi)[i] = h;
    ((ushort4*)lo)[i] = l;
  } else {
    int c = (blk - 1024) * 256 + threadIdx.x;
    #pragma unroll
    for (int k = 0; k < 25; ++k) dwT[k * 512 + c] = dw_w[c * 25 + k];
  }
}

// ---------------------------------------------------------------------------
// MFMA GEMM body (shared by fused-QKV and O-proj): Y[.,512]=A@W^T+b, 3-pass.
// ---------------------------------------------------------------------------
__device__ __forceinline__ void gemm_body(
    const ushort* __restrict__ Ahi, const ushort* __restrict__ Alo,
    const ushort* __restrict__ Bhi, const ushort* __restrict__ Blo,
    const float* __restrict__ bias, float* __restrict__ Y,
    int m0, int n0, ushort* lds) {
  ushort* sAhi = lds;
  ushort* sAlo = lds + 8192;
  ushort* sBhi = lds + 16384;
  ushort* sBlo = lds + 20480;
  int tid = threadIdx.x;
  int lane = tid & 63;
  int w = tid >> 6;
  int wr = (w >> 1) * 64;
  int wc = (w & 1) * 32;
  int l8r = lane >> 3;
  int sll = ((lane & 7) ^ l8r) << 3;
  int l16 = lane & 15, lq = lane >> 4;

  f32x4 acc[4][2];
  f32x4 zero = {0.f, 0.f, 0.f, 0.f};
  #pragma unroll
  for (int m = 0; m < 4; ++m)
    #pragma unroll
    for (int n = 0; n < 2; ++n) acc[m][n] = zero;

  for (int kt = 0; kt < 8; ++kt) {
    int kk = kt * 64;
    __syncthreads();
    #pragma unroll
    for (int q = 0; q < 4; ++q) {
      int ci = w * 4 + q;
      size_t go = (size_t)(m0 + ci * 8 + l8r) * 512 + kk + sll;
      GLOAD16(Ahi + go, sAhi + ci * 512);
      GLOAD16(Alo + go, sAlo + ci * 512);
    }
    #pragma unroll
    for (int q = 0; q < 2; ++q) {
      int ci = w * 2 + q;
      size_t go = (size_t)(n0 + ci * 8 + l8r) * 512 + kk + sll;
      GLOAD16(Bhi + go, sBhi + ci * 512);
      GLOAD16(Blo + go, sBlo + ci * 512);
    }
    __syncthreads();
    #pragma unroll
    for (int ks = 0; ks < 2; ++ks) {
      int slot = ks * 4 + lq;
      bf16x8 ah[4], al[4], bh[2], bl[2];
      #pragma unroll
      for (int m = 0; m < 4; ++m) {
        int r = wr + m * 16 + l16;
        int ph = (slot ^ (r & 7)) << 3;
        ah[m] = *(const bf16x8*)&sAhi[r * 64 + ph];
        al[m] = *(const bf16x8*)&sAlo[r * 64 + ph];
      }
      #pragma unroll
      for (int n = 0; n < 2; ++n) {
        int r = wc + n * 16 + l16;
        int ph = (slot ^ (r & 7)) << 3;
        bh[n] = *(const bf16x8*)&sBhi[r * 64 + ph];
        bl[n] = *(const bf16x8*)&sBlo[r * 64 + ph];
      }
      #pragma unroll
      for (int m = 0; m < 4; ++m)
        #pragma unroll
        for (int n = 0; n < 2; ++n) {
          acc[m][n] = MFMA16(ah[m], bh[n], acc[m][n]);
          acc[m][n] = MFMA16(ah[m], bl[n], acc[m][n]);
          acc[m][n] = MFMA16(al[m], bh[n], acc[m][n]);
        }
    }
  }
  #pragma unroll
  for (int n = 0; n < 2; ++n) {
    int col = n0 + wc + n * 16 + l16;
    float bv = bias[col];
    #pragma unroll
    for (int m = 0; m < 4; ++m) {
      #pragma unroll
      for (int j = 0; j < 4; ++j) {
        int row = m0 + wr + m * 16 + lq * 4 + j;
        Y[(size_t)row * 512 + col] = acc[m][n][j] + bv;
      }
    }
  }
}

__global__ __launch_bounds__(256) void gemm_qkv(
    const ushort* __restrict__ Ahi, const ushort* __restrict__ Alo,
    const ushort* __restrict__ Wh0, const ushort* __restrict__ Wl0,
    const ushort* __restrict__ Wh1, const ushort* __restrict__ Wl1,
    const ushort* __restrict__ Wh2, const ushort* __restrict__ Wl2,
    const float* __restrict__ b0, const float* __restrict__ b1,
    const float* __restrict__ b2, float* __restrict__ Y0,
    float* __restrict__ Y1, float* __restrict__ Y2) {
  __shared__ ushort lds[24576];
  int which = blockIdx.x >> 3;
  int n0 = (blockIdx.x & 7) * 64;
  int m0 = blockIdx.y * 128;
  const ushort* Bh; const ushort* Bl; const float* bb; float* Y;
  if (which == 0)      { Bh = Wh0; Bl = Wl0; bb = b0; Y = Y0; }
  else if (which == 1) { Bh = Wh1; Bl = Wl1; bb = b1; Y = Y1; }
  else                 { Bh = Wh2; Bl = Wl2; bb = b2; Y = Y2; }
  gemm_body(Ahi, Alo, Bh, Bl, bb, Y, m0, n0, lds);
}

__global__ __launch_bounds__(256) void gemm_mfma(
    const ushort* __restrict__ Ahi, const ushort* __restrict__ Alo,
    const ushort* __restrict__ Bhi, const ushort* __restrict__ Blo,
    const float* __restrict__ bias, float* __restrict__ Y) {
  __shared__ ushort lds[24576];
  gemm_body(Ahi, Alo, Bhi, Blo, bias, Y, blockIdx.y * 128, blockIdx.x * 64, lds);
}

// ---------------------------------------------------------------------------
// Offset network v2 (register sliding-window depthwise conv).
// ---------------------------------------------------------------------------
__global__ __launch_bounds__(256) void offset_net2(
    const float* __restrict__ x, const float* __restrict__ dwT,
    const float* __restrict__ dw_b, const float* __restrict__ off_w,
    float* __restrict__ samp) {
  __shared__ float wT[16][516];
  __shared__ float hT[16][516];
  __shared__ float ofs[16][16];
  int x0 = blockIdx.x * 16;
  int y = blockIdx.y;
  int b = blockIdx.z;
  int tid = threadIdx.x;

  for (int e = tid; e < 2048; e += 256) {
    int o = e >> 7, c4 = e & 127;
    *(float4*)&wT[o][c4 * 4] = *(const float4*)&off_w[o * 512 + c4 * 4];
  }

  int c = tid * 2;
  float2 dwv[25];
  #pragma unroll
  for (int k = 0; k < 25; ++k) dwv[k] = *(const float2*)&dwT[k * 512 + c];
  float2 cb = *(const float2*)&dw_b[c];

  const float* xb = x + (size_t)b * 1024 * 512 + c;
  bool rv[5];
  #pragma unroll
  for (int r = 0; r < 5; ++r) {
    int yy = y - 2 + r;
    rv[r] = (yy >= 0 && yy < 32);
  }
  float2 win[5][5];
  #pragma unroll
  for (int j = 0; j < 4; ++j) {
    int xc = x0 - 2 + j;
    bool cvld = (xc >= 0 && xc < 32);
    #pragma unroll
    for (int r = 0; r < 5; ++r) {
      win[r][j] = (rv[r] && cvld)
          ? *(const float2*)&xb[(size_t)((y - 2 + r) * 32 + xc) * 512]
          : make_float2(0.f, 0.f);
    }
  }
  #pragma unroll
  for (int i = 0; i < 16; ++i) {
    int xc = x0 + i + 2;
    bool cvld = (xc < 32);
    #pragma unroll
    for (int r = 0; r < 5; ++r) {
      win[r][4] = (rv[r] && cvld)
          ? *(const float2*)&xb[(size_t)((y - 2 + r) * 32 + xc) * 512]
          : make_float2(0.f, 0.f);
    }
    float sx = cb.x, sy = cb.y;
    #pragma unroll
    for (int r = 0; r < 5; ++r)
      #pragma unroll
      for (int j = 0; j < 5; ++j) {
        sx += win[r][j].x * dwv[r * 5 + j].x;
        sy += win[r][j].y * dwv[r * 5 + j].y;
      }
    float g0 = 0.5f * sx * (1.0f + erff(sx * 0.70710678118654752f));
    float g1 = 0.5f * sy * (1.0f + erff(sy * 0.70710678118654752f));
    *(float2*)&hT[i][c] = make_float2(g0, g1);
    #pragma unroll
    for (int r = 0; r < 5; ++r) {
      win[r][0] = win[r][1]; win[r][1] = win[r][2];
      win[r][2] = win[r][3]; win[r][3] = win[r][4];
    }
  }
  __syncthreads();

  {
    int o = tid & 15, px = tid >> 4;
    float acc = 0.f;
    #pragma unroll 4
    for (int c4 = 0; c4 < 128; ++c4) {
      float4 hv = *(const float4*)&hT[px][c4 * 4];
      float4 wv = *(const float4*)&wT[o][c4 * 4];
      acc += hv.x * wv.x + hv.y * wv.y + hv.z * wv.z + hv.w * wv.w;
    }
    ofs[px][o] = tanhf(acc) * 2.0f;
  }
  __syncthreads();

  if (tid < 128) {
    int px = tid >> 3, h = tid & 7;
    int n = y * 32 + x0 + px;
    float gx = -1.0f + 2.0f * (float)(x0 + px) / 31.0f;
    float gy = -1.0f + 2.0f * (float)y / 31.0f;
    float sx = fminf(fmaxf(gx + ofs[px][2 * h], -1.0f), 1.0f);
    float sy = fminf(fmaxf(gy + ofs[px][2 * h + 1], -1.0f), 1.0f);
    float2 pc;
    pc.x = (sx + 1.0f) * 16.0f - 0.5f;
    pc.y = (sy + 1.0f) * 16.0f - 0.5f;
    ((float2*)samp)[(size_t)(b * 8 + h) * 1024 + n] = pc;
  }
}

// ---------------------------------------------------------------------------
// Bilinear grid-sample of K and V -> Ks hi/lo [bh][1024][64], Vt [bh][64][1024]
// ---------------------------------------------------------------------------
__global__ __launch_bounds__(256) void grid_sample(
    const float* __restrict__ K, const float* __restrict__ V,
    const float* __restrict__ samp, ushort* __restrict__ Ksh,
    ushort* __restrict__ Ksl, ushort* __restrict__ Vt) {
  __shared__ ushort sV[64][72];
  int bh = blockIdx.y;
  int b = bh >> 3, h = bh & 7;
  int jb = blockIdx.x;
  int d = threadIdx.x & 63;
  for (int p = 0; p < 16; ++p) {
    int jl = p * 4 + (threadIdx.x >> 6);
    int j = jb * 64 + jl;
    float2 pc = ((const float2*)samp)[(size_t)bh * 1024 + j];
    float gx = pc.x, gy = pc.y;
    float x0 = floorf(gx), y0 = floorf(gy);
    float aK = 0.f, aV = 0.f;
    #pragma unroll
    for (int dy = 0; dy < 2; ++dy)
      #pragma unroll
      for (int dx = 0; dx < 2; ++dx) {
        float xi = x0 + (float)dx, yi = y0 + (float)dy;
        float wgt = (1.0f - fabsf(gx - xi)) * (1.0f - fabsf(gy - yi));
        if (xi >= 0.f && xi < 32.f && yi >= 0.f && yi < 32.f) {
          size_t base = ((size_t)b * 1024 + (int)yi * 32 + (int)xi) * 512 + h * 64 + d;
          aK += K[base] * wgt;
          aV += V[base] * wgt;
        }
      }
    ushort kh = f2bf(aK);
    size_t o = ((size_t)bh * 1024 + j) * 64 + d;
    Ksh[o] = kh;
    Ksl[o] = f2bf(aK - bf2f(kh));
    sV[jl][d] = f2bf(aV);
  }
  __syncthreads();
  int dd = threadIdx.x >> 2, c4 = threadIdx.x & 3;
  bf16x8 v0, v1;
  #pragma unroll
  for (int k = 0; k < 8; ++k) v0[k] = (short)sV[c4 * 16 + k][dd];
  #pragma unroll
  for (int k = 0; k < 8; ++k) v1[k] = (short)sV[c4 * 16 + 8 + k][dd];
  size_t o = ((size_t)bh * 64 + dd) * 1024 + jb * 64 + c4 * 16;
  *(bf16x8*)&Vt[o] = v0;
  *(bf16x8*)&Vt[o + 8] = v1;
}

// ---------------------------------------------------------------------------
// Relative-position bias via 4-tap bicubic along both axes.
// ---------------------------------------------------------------------------
__device__ __forceinline__ void bicubic_taps(int i, float* w, int* idx) {
  const float a = -0.75f;
  float src = ((float)i + 0.5f) * 0.0625f - 0.5f;
  float fi = floorf(src);
  int i0 = (int)fi;
  float t = src - fi;
  #pragma unroll
  for (int k = -1; k <= 2; ++k) {
    float d = fabsf(t - (float)k);
    float wv;
    if (d <= 1.0f)
      wv = ((a + 2.0f) * d - (a + 3.0f)) * d * d + 1.0f;
    else if (d < 2.0f)
      wv = a * (((d - 5.0f) * d + 8.0f) * d - 4.0f);
    else
      wv = 0.0f;
    int ic = i0 + k;
    ic = ic < 0 ? 0 : (ic > 63 ? 63 : ic);
    w[k + 1] = wv;
    idx[k + 1] = ic;
  }
}

__global__ __launch_bounds__(256) void bias_kernel(
    const float* __restrict__ table, float* __restrict__ bias) {
  __shared__ float tab[225];
  int i = blockIdx.x;
  int tid = threadIdx.x;
  if (tid < 225) tab[tid] = table[tid];
  __syncthreads();
  float wA[4]; int iA[4];
  bicubic_taps(i, wA, iA);
  for (int j = tid; j < 1024; j += 256) {
    float wB[4]; int iB[4];
    bicubic_taps(j, wB, iB);
    float sum = 0.f;
    #pragma unroll
    for (int ka = 0; ka < 4; ++ka) {
      int pa = iA[ka];
      int py = pa >> 3, px = pa & 7;
      float wa = wA[ka];
      #pragma unroll
      for (int kb = 0; kb < 4; ++kb) {
        int qb = iB[kb];
        int qy = qb >> 3, qx = qb & 7;
        sum += wa * wB[kb] * tab[(py - qy + 7) * 15 + (px - qx + 7)];
      }
    }
    bias[(size_t)i * 1024 + j] = sum;
  }
}

// ---------------------------------------------------------------------------
// MFMA flash attention v2: Q fragments in registers, K/V LDS double-buffered,
// single __syncthreads per KV-tile (stage jt+1 issued before compute of jt),
// bias prefetched one tile ahead into registers.
// ---------------------------------------------------------------------------
__global__ __launch_bounds__(256) void attn_mfma(
    const float* __restrict__ Q, const ushort* __restrict__ Kh,
    const ushort* __restrict__ Kl, const ushort* __restrict__ Vt,
    const float* __restrict__ bias, ushort* __restrict__ Oh,
    ushort* __restrict__ Ol) {
  __shared__ ushort sKh[2][4096];
  __shared__ ushort sKl[2][4096];
  __shared__ ushort sVt[2][4096];
  __shared__ ushort sP[4][1152];

  int tid = threadIdx.x;
  int lane = tid & 63;
  int w = tid >> 6;
  int l16 = lane & 15, lq = lane >> 4;
  int bh = blockIdx.y;
  int b = bh >> 3, h = bh & 7;
  int i0 = blockIdx.x * 64;
  int r8 = lane >> 3, ch = lane & 7;

  // Q fragments (this wave's 16 rows) straight into registers, *0.125
  bf16x8 qh[2], ql[2];
  #pragma unroll
  for (int s = 0; s < 2; ++s) {
    const float* qp =
        Q + ((size_t)b * 1024 + i0 + w * 16 + l16) * 512 + h * 64 + s * 32 + lq * 8;
    #pragma unroll
    for (int j = 0; j < 8; ++j) {
      float f = qp[j] * 0.125f;
      ushort hb = f2bf(f);
      qh[s][j] = (short)hb;
      ql[s][j] = (short)f2bf(f - bf2f(hb));
    }
  }

  f32x4 oacc[4];
  f32x4 zero = {0.f, 0.f, 0.f, 0.f};
  #pragma unroll
  for (int n = 0; n < 4; ++n) oacc[n] = zero;
  float mrow[4], lrow[4];
  #pragma unroll
  for (int r = 0; r < 4; ++r) { mrow[r] = -INFINITY; lrow[r] = 0.f; }

  ushort* myP = sP[w];
  int stgrow0 = w * 16;      // this wave stages rows [w*16, w*16+16)
  int grow0 = stgrow0 + r8;  // + q*8

  // ---- prologue: stage tile 0 into buf 0; preload bias(0) ----
  #pragma unroll
  for (int q = 0; q < 2; ++q) {
    int row = grow0 + q * 8;
    int gch = ch ^ (row & 7);
    size_t gk = ((size_t)bh * 1024 + row) * 64 + gch * 8;
    GLOAD16(Kh + gk, &sKh[0][(stgrow0 + q * 8) * 64]);
    GLOAD16(Kl + gk, &sKl[0][(stgrow0 + q * 8) * 64]);
    size_t gv = ((size_t)bh * 64 + row) * 1024 + gch * 8;
    GLOAD16(Vt + gv, &sVt[0][(stgrow0 + q * 8) * 64]);
  }
  f32x4 bias_c[4];
  {
    const float* bp = bias + (size_t)(i0 + w * 16 + lq * 4) * 1024;
    #pragma unroll
    for (int n = 0; n < 4; ++n)
      #pragma unroll
      for (int r = 0; r < 4; ++r)
        bias_c[n][r] = bp[(size_t)r * 1024 + n * 16 + l16];
  }
  __syncthreads();

  int cur = 0;
  for (int jt = 0; jt < 16; ++jt) {
    // ---- issue stage of tile jt+1 into the other buffer ----
    if (jt < 15) {
      #pragma unroll
      for (int q = 0; q < 2; ++q) {
        int row = grow0 + q * 8;
        int gch = ch ^ (row & 7);
        size_t gk = ((size_t)bh * 1024 + (jt + 1) * 64 + row) * 64 + gch * 8;
        GLOAD16(Kh + gk, &sKh[cur ^ 1][(stgrow0 + q * 8) * 64]);
        GLOAD16(Kl + gk, &sKl[cur ^ 1][(stgrow0 + q * 8) * 64]);
        size_t gv = ((size_t)bh * 64 + row) * 1024 + (jt + 1) * 64 + gch * 8;
        GLOAD16(Vt + gv, &sVt[cur ^ 1][(stgrow0 + q * 8) * 64]);
      }
    }
    // consume preloaded bias; prefetch next tile's bias
    f32x4 sacc[4];
    #pragma unroll
    for (int n = 0; n < 4; ++n) sacc[n] = bias_c[n];
    if (jt < 15) {
      const float* bp =
          bias + (size_t)(i0 + w * 16 + lq * 4) * 1024 + (jt + 1) * 64;
      #pragma unroll
      for (int n = 0; n < 4; ++n)
        #pragma unroll
        for (int r = 0; r < 4; ++r)
          bias_c[n][r] = bp[(size_t)r * 1024 + n * 16 + l16];
    }
    // ---- QK^T (3-pass hi/lo), A from registers ----
    #pragma unroll
    for (int ks = 0; ks < 2; ++ks) {
      int cslot = ((ks * 4 + lq) ^ (l16 & 7)) * 8;
      #pragma unroll
      for (int n = 0; n < 4; ++n) {
        int brow = (n * 16 + l16) * 64;
        bf16x8 bH = *(const bf16x8*)&sKh[cur][brow + cslot];
        bf16x8 bL = *(const bf16x8*)&sKl[cur][brow + cslot];
        sacc[n] = MFMA16(qh[ks], bH, sacc[n]);
        sacc[n] = MFMA16(qh[ks], bL, sacc[n]);
        sacc[n] = MFMA16(ql[ks], bH, sacc[n]);
      }
    }
    // ---- online softmax (C-layout rows), P -> per-wave LDS tile ----
    #pragma unroll
    for (int r = 0; r < 4; ++r) {
      float mt = fmaxf(fmaxf(sacc[0][r], sacc[1][r]), fmaxf(sacc[2][r], sacc[3][r]));
      #pragma unroll
      for (int msk = 1; msk < 16; msk <<= 1) mt = fmaxf(mt, __shfl_xor(mt, msk));
      float mn = fmaxf(mrow[r], mt);
      float sc = __expf(mrow[r] - mn);
      float ts = 0.f;
      #pragma unroll
      for (int n = 0; n < 4; ++n) {
        float p = __expf(sacc[n][r] - mn);
        ts += p;
        myP[(lq * 4 + r) * 72 + n * 16 + l16] = f2bf(p);
      }
      #pragma unroll
      for (int msk = 1; msk < 16; msk <<= 1) ts += __shfl_xor(ts, msk);
      lrow[r] = lrow[r] * sc + ts;
      mrow[r] = mn;
      #pragma unroll
      for (int n = 0; n < 4; ++n) oacc[n][r] *= sc;
    }
    // ---- PV: A = P [16q][64k] (per-wave), B = V^T [16d][64k] ----
    #pragma unroll
    for (int ks = 0; ks < 2; ++ks) {
      bf16x8 pa = *(const bf16x8*)&myP[l16 * 72 + (ks * 4 + lq) * 8];
      int cslot = ((ks * 4 + lq) ^ (l16 & 7)) * 8;
      #pragma unroll
      for (int n = 0; n < 4; ++n) {
        bf16x8 bv = *(const bf16x8*)&sVt[cur][(n * 16 + l16) * 64 + cslot];
        oacc[n] = MFMA16(pa, bv, oacc[n]);
      }
    }
    __syncthreads();  // drains stage(jt+1); all waves done reading buf cur
    cur ^= 1;
  }
  // ---- epilogue ----
  #pragma unroll
  for (int r = 0; r < 4; ++r) {
    float inv = 1.0f / lrow[r];
    int qr = i0 + w * 16 + lq * 4 + r;
    #pragma unroll
    for (int n = 0; n < 4; ++n) {
      float v = oacc[n][r] * inv;
      ushort hb = f2bf(v);
      size_t o = ((size_t)b * 1024 + qr) * 512 + h * 64 + n * 16 + l16;
      Oh[o] = hb;
      Ol[o] = f2bf(v - bf2f(hb));
    }
  }
}

// ---------------------------------------------------------------------------
extern "C" void kernel_launch(void* const* d_in, const int* in_sizes, int n_in,
                              void* d_out, int out_size, void* d_ws, size_t ws_size,
                              hipStream_t stream) {
  const float* x     = (const float*)d_in[0];
  const float* q_w   = (const float*)d_in[1];
  const float* q_b   = (const float*)d_in[2];
  const float* k_w   = (const float*)d_in[3];
  const float* k_b   = (const float*)d_in[4];
  const float* v_w   = (const float*)d_in[5];
  const float* v_b   = (const float*)d_in[6];
  const float* o_w   = (const float*)d_in[7];
  const float* o_b   = (const float*)d_in[8];
  const float* dw_w  = (const float*)d_in[9];
  const float* dw_b  = (const float*)d_in[10];
  const float* off_w = (const float*)d_in[11];
  const float* btab  = (const float*)d_in[12];

  float* ws = (float*)d_ws;
  const size_t SZ = (size_t)4 * 1024 * 512;  // 2M elements
  float* Q    = ws;
  float* K    = ws + SZ;
  float* V    = ws + 2 * SZ;
  float* bias = ws + 3 * SZ;                 // 1M floats
  float* samp = ws + 3 * SZ + 1048576;       // 65536 floats

  ushort* u = (ushort*)(samp + 65536);
  ushort* Xhi  = u;                          // 2M each
  ushort* Xlo  = Xhi + SZ;
  ushort* Wq_h = Xlo + SZ;                   // 256K each, 8 buffers
  ushort* Wq_l = Wq_h + 262144;
  ushort* Wk_h = Wq_h + 2 * 262144;
  ushort* Wk_l = Wq_h + 3 * 262144;
  ushort* Wv_h = Wq_h + 4 * 262144;
  ushort* Wv_l = Wq_h + 5 * 262144;
  ushort* Wo_h = Wq_h + 6 * 262144;
  ushort* Wo_l = Wq_h + 7 * 262144;
  ushort* Ksh  = Wq_h + 8 * 262144;          // 2M each
  ushort* Ksl  = Ksh + SZ;
  ushort* Vtr  = Ksl + SZ;
  ushort* Aoh  = Vtr + SZ;
  ushort* Aol  = Aoh + SZ;
  float* dwT   = (float*)(Aol + SZ);         // 25*512 floats

  split_kernel<<<2048, 256, 0, stream>>>(x, Xhi, Xlo, 524288);
  prep_weights<<<1026, 256, 0, stream>>>(q_w, k_w, v_w, o_w, dw_w, Wq_h, Wq_l,
                                         Wk_h, Wk_l, Wv_h, Wv_l, Wo_h, Wo_l, dwT);

  gemm_qkv<<<dim3(24, 32), 256, 0, stream>>>(Xhi, Xlo, Wq_h, Wq_l, Wk_h, Wk_l,
                                             Wv_h, Wv_l, q_b, k_b, v_b, Q, K, V);

  offset_net2<<<dim3(2, 32, 4), 256, 0, stream>>>(x, dwT, dw_b, off_w, samp);
  bias_kernel<<<1024, 256, 0, stream>>>(btab, bias);
  grid_sample<<<dim3(16, 32), 256, 0, stream>>>(K, V, samp, Ksh, Ksl, Vtr);

  attn_mfma<<<dim3(16, 32), 256, 0, stream>>>(Q, Ksh, Ksl, Vtr, bias, Aoh, Aol);

  gemm_mfma<<<dim3(8, 32), 256, 0, stream>>>(Aoh, Aol, Wo_h, Wo_l, o_b,
                                             (float*)d_out);
}